// Round 9
// baseline (259.690 us; speedup 1.0000x reference)
//
#include <hip/hip_runtime.h>
#include <hip/hip_cooperative_groups.h>
#include <math.h>

namespace cg = cooperative_groups;

#define BATCH  8192
#define NNODES 500000
#define DIM    128
#define TDIM   64
#define KNB    32
#define KSEL   16

// bf16 weight pool element offsets
#define OFF_W1   0
#define OFF_W2   40960
#define OFF_WIH  57344
#define OFF_WHH  106496
#define OFF_WQ   155648
#define OFF_WV   172032
#define OFF_WO   196608
#define OFF_WM1  212992
#define OFF_WM2  245760
#define OFF_WKT  262144
#define CVT_TOT  286720

#define GRIDB  256
#define BLKT   512
#define NTHREADS (GRIDB * BLKT)

typedef float  f32x4  __attribute__((ext_vector_type(4)));
typedef __bf16 bf16x8 __attribute__((ext_vector_type(8)));
typedef short  s16x8  __attribute__((ext_vector_type(8)));

#define MFMA(a,b,c) __builtin_amdgcn_mfma_f32_16x16x32_bf16(a,b,c,0,0,0)

__device__ __forceinline__ float sigmoidf_(float x) { return 1.f / (1.f + expf(-x)); }
__device__ __forceinline__ unsigned short f2bf(float x) {
    unsigned u = __builtin_bit_cast(unsigned, x);
    unsigned r = (u + 0x7FFFu + ((u >> 16) & 1u)) >> 16;
    return (unsigned short)r;
}
__device__ __forceinline__ float bf2f(unsigned short u) {
    unsigned v = ((unsigned)u) << 16;
    return __builtin_bit_cast(float, v);
}
__device__ __forceinline__ bf16x8 ldfrag(const unsigned short* p) {
    s16x8 v = *(const s16x8*)p;
    return __builtin_bit_cast(bf16x8, v);
}
__device__ __forceinline__ uint2 pack4bf(float4 v) {
    uint2 pk;
    pk.x = (unsigned)f2bf(v.x) | ((unsigned)f2bf(v.y) << 16);
    pk.y = (unsigned)f2bf(v.z) | ((unsigned)f2bf(v.w) << 16);
    return pk;
}

struct MegaParams {
    const int   *src, *dst;
    const float *ts;
    const int   *nbr_ids; const float *nbr_ts;
    const float *memory, *last_update;
    const float *w_t_msg, *b_t_msg, *W_msg1, *b_msg1, *W_msg2, *b_msg2;
    const float *W_ih, *b_ih, *W_hh, *b_hh;
    const float *w_t_att, *b_t_att;
    const float *Wq, *bq, *Wk, *bk, *Wv, *bv, *Wo, *bo;
    const float *Wm1, *bm1, *Wm2, *bm2, *ln_g, *ln_b;
    float *out;
    float *new_mem; int *winner; int *sel_id; float *sel_td; int *sel_mk;
    unsigned short *Wpool;
};

union ShU {
    struct {                                  // phase 1 (k1): ~60 KB
        unsigned short sxb[64][328];
        unsigned short hb [64][136];
        int   s_node[64];
        int   s_oth [64];
        float s_dt  [64];
    } a;
    struct {                                  // phase 2 (k3): ~129.8 KB
        unsigned short s_nfB[32][136];
        unsigned short s_qB [32][136];
        unsigned short s_u  [32][2][200];
        unsigned short s_kvb[32][2][200];
        unsigned long long pool64[6400];
        const float* s_nptr[32][16];
        float s_td [32][16];
        int   s_mk [32][16];
        float s_qb [32][2];
        float s_satt[32][2];
        float s_at [8][2][16];
        const float* s_ptr[32];
    } b;
};

// ---------------------------------------------------------------------------
// Mega cooperative kernel: prep -> grid.sync -> k1 -> grid.sync -> k3.
// 256 blocks x 512 threads, 1 block/CU (LDS-bound).
// ---------------------------------------------------------------------------
__global__ __launch_bounds__(512) void k_mega(MegaParams P)
{
    __shared__ ShU sh;

    const int tid  = threadIdx.x;
    const int bid  = blockIdx.x;
    const int gtid = bid * BLKT + tid;

    // ======================= phase 0: prep ==================================
    {
        // weight -> bf16 pool (grid-stride)
        for (int i = gtid; i < CVT_TOT; i += NTHREADS) {
            float v;
            if      (i < OFF_W2)  { v = P.W_msg1[i - OFF_W1 ]; }
            else if (i < OFF_WIH) { v = P.W_msg2[i - OFF_W2 ]; }
            else if (i < OFF_WHH) { v = P.W_ih  [i - OFF_WIH]; }
            else if (i < OFF_WQ)  { v = P.W_hh  [i - OFF_WHH]; }
            else if (i < OFF_WV)  { v = P.Wq    [i - OFF_WQ ]; }
            else if (i < OFF_WO)  { v = P.Wv    [i - OFF_WV ]; }
            else if (i < OFF_WM1) { v = P.Wo    [i - OFF_WO ]; }
            else if (i < OFF_WM2) { v = P.Wm1   [i - OFF_WM1]; }
            else if (i < OFF_WKT) { v = P.Wm2   [i - OFF_WM2]; }
            else {
                int j = i - OFF_WKT;           // h*12288 + c*64 + dh
                int h = j / 12288, rem = j % 12288;
                int c = rem >> 6, dh = rem & 63;
                v = P.Wk[(size_t)(h * 64 + dh) * 192 + c];
            }
            P.Wpool[i] = f2bf(v);
        }
        // winner scatter (last-write-wins via atomicMax)
        if (gtid < 2 * BATCH) {
            int v = (gtid < BATCH) ? P.src[gtid] : P.dst[gtid - BATCH];
            atomicMax(&P.winner[v], gtid);
        }
        // temporal top-16-of-32
        int tb = gtid - 2 * BATCH;
        if (tb >= 0 && tb < BATCH) {
            int   s = P.src[tb];
            float t = P.ts[tb];
            const int*   ip = P.nbr_ids + (size_t)s * KNB;
            const float* tp = P.nbr_ts  + (size_t)s * KNB;
            float kt[KNB]; int kid[KNB];
            #pragma unroll
            for (int j = 0; j < KNB; ++j) {
                int id = ip[j]; float nt = tp[j];
                bool valid = (id >= 0) && (nt < t + 1e-6f);
                kt[j]  = valid ? nt : -1e30f;
                kid[j] = id;
            }
            unsigned picked = 0u;
            for (int sI = 0; sI < KSEL; ++sI) {
                float bv = -3.4e38f; int bj = 0; int bid2 = 0;
                #pragma unroll
                for (int j = 0; j < KNB; ++j) {
                    bool avail = !((picked >> j) & 1u);
                    if (avail && kt[j] > bv) { bv = kt[j]; bj = j; bid2 = kid[j]; }
                }
                picked |= (1u << bj);
                bool mk = bv > -1e29f;
                int id = mk ? (bid2 < 0 ? 0 : (bid2 > NNODES - 1 ? NNODES - 1 : bid2)) : 0;
                P.sel_id[tb * KSEL + sI] = id;
                P.sel_td[tb * KSEL + sI] = mk ? (t - bv) : 0.f;
                P.sel_mk[tb * KSEL + sI] = mk ? 1 : 0;
            }
        }
    }
    __threadfence();
    cg::this_grid().sync();

    // ======================= phase 1: k1 (msg MLP + GRU) ====================
    {
        auto& sxb    = sh.a.sxb;
        auto& hb     = sh.a.hb;
        auto& s_node = sh.a.s_node;
        auto& s_oth  = sh.a.s_oth;
        auto& s_dt   = sh.a.s_dt;

        const unsigned short* W1b  = P.Wpool + OFF_W1;
        const unsigned short* W2b  = P.Wpool + OFF_W2;
        const unsigned short* Wihb = P.Wpool + OFF_WIH;
        const unsigned short* Whhb = P.Wpool + OFF_WHH;

        const int base = bid * 64;

        if (tid < 64) {
            int gi = base + tid;
            int node, oth; float t;
            if (gi < BATCH) { node = P.src[gi];         oth = P.dst[gi];         t = P.ts[gi]; }
            else            { node = P.dst[gi - BATCH]; oth = P.src[gi - BATCH]; t = P.ts[gi - BATCH]; }
            s_node[tid] = node;
            s_oth[tid]  = oth;
            s_dt[tid]   = t - P.last_update[node];
        }
        __syncthreads();

        for (int idx = tid; idx < 64 * 32; idx += 512) {
            int r = idx >> 5, c4 = (idx & 31) << 2;
            float4 vs = *(const float4*)&P.memory[(size_t)s_node[r] * DIM + c4];
            float4 vo = *(const float4*)&P.memory[(size_t)s_oth[r]  * DIM + c4];
            *(uint2*)&sxb[r][c4]       = pack4bf(vs);
            *(uint2*)&sxb[r][128 + c4] = pack4bf(vo);
        }
        for (int idx = tid; idx < 64 * TDIM; idx += 512) {
            int r = idx >> 6, c = idx & 63;
            float f = s_dt[r] * P.w_t_msg[c] + P.b_t_msg[c];
            sxb[r][256 + c] = f2bf((c & 1) ? cosf(f) : sinf(f));
        }
        __syncthreads();

        const int w    = tid >> 6;
        const int l    = tid & 63;
        const int rowA = l & 15;
        const int kg   = l >> 4;
        const int n0   = w * 16;
        const int col  = l & 15;
        const int rgrp = l >> 4;

        // stage 1: h1 = relu(x @ W1^T + b1), K=320
        {
            f32x4 a0 = {0.f,0.f,0.f,0.f}, a1 = {0.f,0.f,0.f,0.f};
            f32x4 a2 = {0.f,0.f,0.f,0.f}, a3 = {0.f,0.f,0.f,0.f};
            #pragma unroll
            for (int kt = 0; kt < 10; ++kt) {
                int ko = kt * 32 + kg * 8;
                bf16x8 bfr = ldfrag(&W1b[(size_t)(n0 + rowA) * 320 + ko]);
                a0 = MFMA(ldfrag(&sxb[     rowA][ko]), bfr, a0);
                a1 = MFMA(ldfrag(&sxb[16 + rowA][ko]), bfr, a1);
                a2 = MFMA(ldfrag(&sxb[32 + rowA][ko]), bfr, a2);
                a3 = MFMA(ldfrag(&sxb[48 + rowA][ko]), bfr, a3);
            }
            float bb = P.b_msg1[n0 + col];
            #pragma unroll
            for (int rgi = 0; rgi < 4; ++rgi) {
                int rb = rgrp * 4 + rgi;
                hb[rb     ][n0 + col] = f2bf(fmaxf(a0[rgi] + bb, 0.f));
                hb[rb + 16][n0 + col] = f2bf(fmaxf(a1[rgi] + bb, 0.f));
                hb[rb + 32][n0 + col] = f2bf(fmaxf(a2[rgi] + bb, 0.f));
                hb[rb + 48][n0 + col] = f2bf(fmaxf(a3[rgi] + bb, 0.f));
            }
        }
        __syncthreads();

        // stage 2: msg = h1 @ W2^T + b2, K=128
        {
            f32x4 m0 = {0.f,0.f,0.f,0.f}, m1 = {0.f,0.f,0.f,0.f};
            f32x4 m2 = {0.f,0.f,0.f,0.f}, m3 = {0.f,0.f,0.f,0.f};
            #pragma unroll
            for (int kt = 0; kt < 4; ++kt) {
                int ko = kt * 32 + kg * 8;
                bf16x8 bfr = ldfrag(&W2b[(size_t)(n0 + rowA) * 128 + ko]);
                m0 = MFMA(ldfrag(&hb[     rowA][ko]), bfr, m0);
                m1 = MFMA(ldfrag(&hb[16 + rowA][ko]), bfr, m1);
                m2 = MFMA(ldfrag(&hb[32 + rowA][ko]), bfr, m2);
                m3 = MFMA(ldfrag(&hb[48 + rowA][ko]), bfr, m3);
            }
            __syncthreads();
            float bb = P.b_msg2[n0 + col];
            #pragma unroll
            for (int rgi = 0; rgi < 4; ++rgi) {
                int rb = rgrp * 4 + rgi;
                hb[rb     ][n0 + col] = f2bf(m0[rgi] + bb);
                hb[rb + 16][n0 + col] = f2bf(m1[rgi] + bb);
                hb[rb + 32][n0 + col] = f2bf(m2[rgi] + bb);
                hb[rb + 48][n0 + col] = f2bf(m3[rgi] + bb);
            }
        }
        __syncthreads();

        // stage 3: GRU gates
        {
            f32x4 g[6][4];
            #pragma unroll
            for (int gi_ = 0; gi_ < 6; ++gi_)
                #pragma unroll
                for (int ta = 0; ta < 4; ++ta) g[gi_][ta] = (f32x4){0.f,0.f,0.f,0.f};
            #pragma unroll
            for (int kt = 0; kt < 4; ++kt) {
                int ko = kt * 32 + kg * 8;
                int br = n0 + rowA;
                bf16x8 bir = ldfrag(&Wihb[(size_t)(      br) * 128 + ko]);
                bf16x8 biz = ldfrag(&Wihb[(size_t)(128 + br) * 128 + ko]);
                bf16x8 big = ldfrag(&Wihb[(size_t)(256 + br) * 128 + ko]);
                bf16x8 bhr = ldfrag(&Whhb[(size_t)(      br) * 128 + ko]);
                bf16x8 bhz = ldfrag(&Whhb[(size_t)(128 + br) * 128 + ko]);
                bf16x8 bhg = ldfrag(&Whhb[(size_t)(256 + br) * 128 + ko]);
                #pragma unroll
                for (int ta = 0; ta < 4; ++ta) {
                    bf16x8 am = ldfrag(&hb [ta * 16 + rowA][ko]);
                    bf16x8 ah = ldfrag(&sxb[ta * 16 + rowA][ko]);
                    g[0][ta] = MFMA(am, bir, g[0][ta]);
                    g[1][ta] = MFMA(am, biz, g[1][ta]);
                    g[2][ta] = MFMA(am, big, g[2][ta]);
                    g[3][ta] = MFMA(ah, bhr, g[3][ta]);
                    g[4][ta] = MFMA(ah, bhz, g[4][ta]);
                    g[5][ta] = MFMA(ah, bhg, g[5][ta]);
                }
            }
            const int d = n0 + col;
            float bir = P.b_ih[d], biz = P.b_ih[128 + d], big = P.b_ih[256 + d];
            float bhr = P.b_hh[d], bhz = P.b_hh[128 + d], bhg = P.b_hh[256 + d];
            #pragma unroll
            for (int ta = 0; ta < 4; ++ta)
                #pragma unroll
                for (int rgi = 0; rgi < 4; ++rgi) {
                    int rr = ta * 16 + rgrp * 4 + rgi;
                    float rv = sigmoidf_((g[0][ta][rgi] + bir) + (g[3][ta][rgi] + bhr));
                    float zv = sigmoidf_((g[1][ta][rgi] + biz) + (g[4][ta][rgi] + bhz));
                    float gv = tanhf((g[2][ta][rgi] + big) + rv * (g[5][ta][rgi] + bhg));
                    float selfv = bf2f(sxb[rr][d]);
                    P.new_mem[(size_t)(base + rr) * DIM + d] = (1.f - zv) * gv + zv * selfv;
                }
        }
    }
    __threadfence();
    cg::this_grid().sync();

    // ======================= phase 2: k3 (attention + MLP + LN) =============
    {
        auto& s_nfB  = sh.b.s_nfB;
        auto& s_qB   = sh.b.s_qB;
        auto& s_u    = sh.b.s_u;
        auto& s_kvb  = sh.b.s_kvb;
        auto& pool64 = sh.b.pool64;
        auto& s_nptr = sh.b.s_nptr;
        auto& s_td   = sh.b.s_td;
        auto& s_mk   = sh.b.s_mk;
        auto& s_qb   = sh.b.s_qb;
        auto& s_satt = sh.b.s_satt;
        auto& s_at   = sh.b.s_at;
        auto& s_ptr  = sh.b.s_ptr;

        const unsigned short* Wqb  = P.Wpool + OFF_WQ;
        const unsigned short* WkTb = P.Wpool + OFF_WKT;
        const unsigned short* Wvb  = P.Wpool + OFF_WV;
        const unsigned short* Wob  = P.Wpool + OFF_WO;
        const unsigned short* Wm1b = P.Wpool + OFF_WM1;
        const unsigned short* Wm2b = P.Wpool + OFF_WM2;

        const int base = bid * 32;

        __syncthreads();   // LDS re-use boundary (phase-1 data dead)

        if (tid < 32) {
            int v = P.src[base + tid];
            int wv = P.winner[v];
            s_ptr[tid] = (wv >= 0) ? (P.new_mem + (size_t)wv * DIM)
                                   : (P.memory  + (size_t)v  * DIM);
        }
        {
            int r = tid >> 4, n = tid & 15;
            int id = P.sel_id[(base + r) * KSEL + n];
            int wi = P.winner[id];
            s_nptr[r][n] = (wi >= 0) ? (P.new_mem + (size_t)wi * DIM)
                                     : (P.memory  + (size_t)id * DIM);
            s_td[r][n] = P.sel_td[(base + r) * KSEL + n];
            s_mk[r][n] = P.sel_mk[(base + r) * KSEL + n];
        }
        __syncthreads();

        for (int idx = tid; idx < 32 * 32; idx += 512) {
            int r = idx >> 5, c4 = (idx & 31) << 2;
            float4 v = *(const float4*)&s_ptr[r][c4];
            *(uint2*)&s_nfB[r][c4] = pack4bf(v);
        }
        __syncthreads();

        const int w    = tid >> 6;
        const int l    = tid & 63;
        const int rowA = l & 15;
        const int kg   = l >> 4;
        const int col  = l & 15;
        const int rgrp = l >> 4;

        // phase 0a: Q = nf @ Wq^T + bq
        {
            const int n0 = w * 16;
            f32x4 q0 = {0.f,0.f,0.f,0.f}, q1 = {0.f,0.f,0.f,0.f};
            #pragma unroll
            for (int kt = 0; kt < 4; ++kt) {
                int ko = kt * 32 + kg * 8;
                bf16x8 bfr = ldfrag(&Wqb[(size_t)(n0 + rowA) * 128 + ko]);
                q0 = MFMA(ldfrag(&s_nfB[     rowA][ko]), bfr, q0);
                q1 = MFMA(ldfrag(&s_nfB[16 + rowA][ko]), bfr, q1);
            }
            float bb = P.bq[n0 + col];
            #pragma unroll
            for (int rgi = 0; rgi < 4; ++rgi) {
                int rb = rgrp * 4 + rgi;
                s_qB[rb     ][n0 + col] = f2bf(q0[rgi] + bb);
                s_qB[rb + 16][n0 + col] = f2bf(q1[rgi] + bb);
            }
        }
        __syncthreads();

        // phase 0b: qb[r][h] = Q_h . bk_h
        if (tid < 256) {
            int r = tid >> 3, rem = tid & 7, h = rem >> 2, p = rem & 3;
            float part = 0.f;
            #pragma unroll
            for (int j = 0; j < 16; ++j) {
                int dd = h * 64 + p * 16 + j;
                part += bf2f(s_qB[r][dd]) * P.bk[dd];
            }
            part += __shfl_xor(part, 1);
            part += __shfl_xor(part, 2);
            if (p == 0) s_qb[r][h] = part;
        }

        // phase 0c: u = Wk_h^T Q_h (wave w: head w>>2, cols (w&3)*48)
        {
            const int h  = w >> 2;
            const int cb = (w & 3) * 48;
            f32x4 u[3][2];
            #pragma unroll
            for (int ct = 0; ct < 3; ++ct)
                #pragma unroll
                for (int ta = 0; ta < 2; ++ta) u[ct][ta] = (f32x4){0.f,0.f,0.f,0.f};
            #pragma unroll
            for (int kt = 0; kt < 2; ++kt) {
                int ko = kt * 32 + kg * 8;
                bf16x8 bfr[3];
                #pragma unroll
                for (int ct = 0; ct < 3; ++ct)
                    bfr[ct] = ldfrag(&WkTb[(size_t)h * 12288 + (size_t)(cb + ct * 16 + rowA) * 64 + ko]);
                #pragma unroll
                for (int ta = 0; ta < 2; ++ta) {
                    bf16x8 av = ldfrag(&s_qB[ta * 16 + rowA][h * 64 + ko]);
                    #pragma unroll
                    for (int ct = 0; ct < 3; ++ct)
                        u[ct][ta] = MFMA(av, bfr[ct], u[ct][ta]);
                }
            }
            #pragma unroll
            for (int ct = 0; ct < 3; ++ct)
                #pragma unroll
                for (int ta = 0; ta < 2; ++ta)
                    #pragma unroll
                    for (int rgi = 0; rgi < 4; ++rgi) {
                        int rr = ta * 16 + rgrp * 4 + rgi;
                        s_u[rr][h][cb + ct * 16 + col] = f2bf(u[ct][ta][rgi]);
                    }
        }
        __syncthreads();

        // phase A: per-wave 4 rows, wave-private, reg-prefetched gather
        {
            unsigned short (*kvbuf)[16][200] = (unsigned short (*)[16][200])pool64;
            float wt = P.w_t_att[l], bt = P.b_t_att[l];
            const int pfn = l >> 5;
            const int pfc = (l & 31) << 2;

            float4 pf[8];
            {
                const int r = w * 4;
                #pragma unroll
                for (int it = 0; it < 8; ++it)
                    pf[it] = *(const float4*)&s_nptr[r][it * 2 + pfn][pfc];
            }

            for (int rr = 0; rr < 4; ++rr) {
                const int r = w * 4 + rr;
                #pragma unroll
                for (int it = 0; it < 8; ++it)
                    *(uint2*)&kvbuf[w][it * 2 + pfn][pfc] = pack4bf(pf[it]);
                #pragma unroll
                for (int n = 0; n < 16; ++n) {
                    float f = s_td[r][n] * wt + bt;
                    kvbuf[w][n][128 + l] = f2bf((l & 1) ? cosf(f) : sinf(f));
                }
                if (rr < 3) {
                    const int rn = r + 1;
                    #pragma unroll
                    for (int it = 0; it < 8; ++it)
                        pf[it] = *(const float4*)&s_nptr[rn][it * 2 + pfn][pfc];
                }
                __builtin_amdgcn_wave_barrier();

                {
                    int h = (l >> 4) & 1, n = l & 15, half = l >> 5;
                    float acc = (half == 0) ? s_qb[r][h] : 0.f;
                    const unsigned short* kvrow = &kvbuf[w][n][half * 96];
                    const unsigned short* urow  = &s_u[r][h][half * 96];
                    #pragma unroll
                    for (int k = 0; k < 96; k += 8) {
                        s16x8 kv8 = *(const s16x8*)&kvrow[k];
                        s16x8 u8  = *(const s16x8*)&urow[k];
                        #pragma unroll
                        for (int j = 0; j < 8; ++j)
                            acc += bf2f((unsigned short)kv8[j]) * bf2f((unsigned short)u8[j]);
                    }
                    acc += __shfl_xor(acc, 32);
                    int mk = s_mk[r][n];
                    float s = mk ? acc * 0.125f : -INFINITY;
                    float mx = s;
                    #pragma unroll
                    for (int m = 1; m < 16; m <<= 1) mx = fmaxf(mx, __shfl_xor(mx, m));
                    float p = (mk && mx > -1e37f) ? expf(s - mx) : 0.f;
                    float den = p;
                    #pragma unroll
                    for (int m = 1; m < 16; m <<= 1) den += __shfl_xor(den, m);
                    float a = (den > 0.f) ? (p / den) : 0.f;
                    if (l < 32) s_at[w][h][n] = a;
                    if (l == 0 || l == 16) s_satt[r][h] = (den > 0.f) ? 1.f : 0.f;
                }
                __builtin_amdgcn_wave_barrier();

                #pragma unroll
                for (int i = 0; i < 3; ++i) {
                    int c = i * 64 + l;
                    float k0 = 0.f, k1 = 0.f;
                    #pragma unroll
                    for (int n = 0; n < 16; ++n) {
                        float v = bf2f(kvbuf[w][n][c]);
                        k0 += s_at[w][0][n] * v;
                        k1 += s_at[w][1][n] * v;
                    }
                    s_kvb[r][0][c] = f2bf(k0);
                    s_kvb[r][1][c] = f2bf(k1);
                }
                __builtin_amdgcn_wave_barrier();
            }
        }
        __syncthreads();

        // phase B: MFMA back-end (pool aliased)
        unsigned short (*s_aoB)[136] = (unsigned short (*)[136])pool64;
        unsigned short (*s_oB )[136] = (unsigned short (*)[136])((char*)pool64 + 8704);
        unsigned short (*s_h1B)[136] = (unsigned short (*)[136])((char*)pool64 + 17408);
        float          (*s_h2 )[128] = (float          (*)[128])((char*)pool64 + 26112);

        {
            const int h  = w >> 2;
            const int c0 = (w & 3) * 16;
            f32x4 o0 = {0.f,0.f,0.f,0.f}, o1 = {0.f,0.f,0.f,0.f};
            #pragma unroll
            for (int kt = 0; kt < 6; ++kt) {
                int ko = kt * 32 + kg * 8;
                bf16x8 bfr = ldfrag(&Wvb[(size_t)(h * 64 + c0 + rowA) * 192 + ko]);
                o0 = MFMA(ldfrag(&s_kvb[     rowA][h][ko]), bfr, o0);
                o1 = MFMA(ldfrag(&s_kvb[16 + rowA][h][ko]), bfr, o1);
            }
            int d0 = h * 64 + c0 + col;
            float bv0 = P.bv[d0];
            #pragma unroll
            for (int rgi = 0; rgi < 4; ++rgi) {
                int rb = rgrp * 4 + rgi;
                s_oB[rb     ][d0] = f2bf(o0[rgi] + s_satt[rb     ][h] * bv0);
                s_oB[rb + 16][d0] = f2bf(o1[rgi] + s_satt[rb + 16][h] * bv0);
            }
        }
        __syncthreads();

        {
            const int n0 = w * 16;
            f32x4 a0 = {0.f,0.f,0.f,0.f}, a1 = {0.f,0.f,0.f,0.f};
            #pragma unroll
            for (int kt = 0; kt < 4; ++kt) {
                int ko = kt * 32 + kg * 8;
                bf16x8 bfr = ldfrag(&Wob[(size_t)(n0 + rowA) * 128 + ko]);
                a0 = MFMA(ldfrag(&s_oB[     rowA][ko]), bfr, a0);
                a1 = MFMA(ldfrag(&s_oB[16 + rowA][ko]), bfr, a1);
            }
            float bb = P.bo[n0 + col];
            #pragma unroll
            for (int rgi = 0; rgi < 4; ++rgi) {
                int rb = rgrp * 4 + rgi;
                s_aoB[rb     ][n0 + col] = f2bf(a0[rgi] + bb);
                s_aoB[rb + 16][n0 + col] = f2bf(a1[rgi] + bb);
            }
        }
        __syncthreads();

        {
            const int n0 = w * 16;
            f32x4 a0 = {0.f,0.f,0.f,0.f}, a1 = {0.f,0.f,0.f,0.f};
            #pragma unroll
            for (int kt = 0; kt < 8; ++kt) {
                int ko = kt * 32 + kg * 8;
                bf16x8 av0 = (kt < 4) ? ldfrag(&s_aoB[     rowA][ko])
                                      : ldfrag(&s_nfB[     rowA][ko - 128]);
                bf16x8 av1 = (kt < 4) ? ldfrag(&s_aoB[16 + rowA][ko])
                                      : ldfrag(&s_nfB[16 + rowA][ko - 128]);
                bf16x8 bfr = ldfrag(&Wm1b[(size_t)(n0 + rowA) * 256 + ko]);
                a0 = MFMA(av0, bfr, a0);
                a1 = MFMA(av1, bfr, a1);
            }
            float bb = P.bm1[n0 + col];
            #pragma unroll
            for (int rgi = 0; rgi < 4; ++rgi) {
                int rb = rgrp * 4 + rgi;
                s_h1B[rb     ][n0 + col] = f2bf(fmaxf(a0[rgi] + bb, 0.f));
                s_h1B[rb + 16][n0 + col] = f2bf(fmaxf(a1[rgi] + bb, 0.f));
            }
        }
        __syncthreads();

        {
            const int n0 = w * 16;
            f32x4 a0 = {0.f,0.f,0.f,0.f}, a1 = {0.f,0.f,0.f,0.f};
            #pragma unroll
            for (int kt = 0; kt < 4; ++kt) {
                int ko = kt * 32 + kg * 8;
                bf16x8 bfr = ldfrag(&Wm2b[(size_t)(n0 + rowA) * 128 + ko]);
                a0 = MFMA(ldfrag(&s_h1B[     rowA][ko]), bfr, a0);
                a1 = MFMA(ldfrag(&s_h1B[16 + rowA][ko]), bfr, a1);
            }
            float bb = P.bm2[n0 + col];
            #pragma unroll
            for (int rgi = 0; rgi < 4; ++rgi) {
                int rb = rgrp * 4 + rgi;
                s_h2[rb     ][n0 + col] = a0[rgi] + bb;
                s_h2[rb + 16][n0 + col] = a1[rgi] + bb;
            }
        }
        __syncthreads();

        // LayerNorm: wave w -> rows w*4 .. w*4+3
        {
            float lg0 = P.ln_g[l], lg1 = P.ln_g[64 + l];
            float lb0 = P.ln_b[l], lb1 = P.ln_b[64 + l];
            #pragma unroll
            for (int i = 0; i < 4; ++i) {
                int r = w * 4 + i;
                float v0 = s_h2[r][l], v1 = s_h2[r][64 + l];
                float sum = v0 + v1;
                #pragma unroll
                for (int m = 1; m < 64; m <<= 1) sum += __shfl_xor(sum, m);
                float mean = sum * (1.f / 128.f);
                float e0 = v0 - mean, e1 = v1 - mean;
                float sq = e0 * e0 + e1 * e1;
                #pragma unroll
                for (int m = 1; m < 64; m <<= 1) sq += __shfl_xor(sq, m);
                float inv = rsqrtf(sq * (1.f / 128.f) + 1e-5f);
                P.out[(size_t)(base + r) * DIM + l]      = e0 * inv * lg0 + lb0;
                P.out[(size_t)(base + r) * DIM + 64 + l] = e1 * inv * lg1 + lb1;
            }
        }
    }
}

// ---------------------------------------------------------------------------
extern "C" void kernel_launch(void* const* d_in, const int* in_sizes, int n_in,
                              void* d_out, int out_size, void* d_ws, size_t ws_size,
                              hipStream_t stream) {
    MegaParams P;
    P.src         = (const int*)  d_in[0];
    P.dst         = (const int*)  d_in[1];
    P.ts          = (const float*)d_in[2];
    P.nbr_ids     = (const int*)  d_in[3];
    P.nbr_ts      = (const float*)d_in[4];
    P.memory      = (const float*)d_in[5];
    P.last_update = (const float*)d_in[6];
    P.w_t_msg     = (const float*)d_in[7];
    P.b_t_msg     = (const float*)d_in[8];
    P.W_msg1      = (const float*)d_in[9];
    P.b_msg1      = (const float*)d_in[10];
    P.W_msg2      = (const float*)d_in[11];
    P.b_msg2      = (const float*)d_in[12];
    P.W_ih        = (const float*)d_in[13];
    P.b_ih        = (const float*)d_in[14];
    P.W_hh        = (const float*)d_in[15];
    P.b_hh        = (const float*)d_in[16];
    P.w_t_att     = (const float*)d_in[17];
    P.b_t_att     = (const float*)d_in[18];
    P.Wq          = (const float*)d_in[19];
    P.bq          = (const float*)d_in[20];
    P.Wk          = (const float*)d_in[21];
    P.bk          = (const float*)d_in[22];
    P.Wv          = (const float*)d_in[23];
    P.bv          = (const float*)d_in[24];
    P.Wo          = (const float*)d_in[25];
    P.bo          = (const float*)d_in[26];
    P.Wm1         = (const float*)d_in[27];
    P.bm1         = (const float*)d_in[28];
    P.Wm2         = (const float*)d_in[29];
    P.bm2         = (const float*)d_in[30];
    P.ln_g        = (const float*)d_in[31];
    P.ln_b        = (const float*)d_in[32];
    P.out         = (float*)d_out;

    char* ws = (char*)d_ws;
    size_t off = 0;
    P.new_mem = (float*)(ws + off); off += (size_t)2 * BATCH * DIM * 4;   // 8 MiB
    P.winner  = (int*)  (ws + off); off += 2097152;                       // 2 MiB
    P.sel_id  = (int*)  (ws + off); off += (size_t)BATCH * KSEL * 4;
    P.sel_td  = (float*)(ws + off); off += (size_t)BATCH * KSEL * 4;
    P.sel_mk  = (int*)  (ws + off); off += (size_t)BATCH * KSEL * 4;
    P.Wpool   = (unsigned short*)(ws + off); off += (size_t)CVT_TOT * 2;

    hipMemsetAsync(P.winner, 0xFF, NNODES * sizeof(int), stream);

    void* kargs[] = { &P };
    hipLaunchCooperativeKernel((const void*)k_mega, dim3(GRIDB), dim3(BLKT),
                               kargs, 0, stream);
}

// Round 10
// 74.833 us; speedup vs baseline: 3.4703x; 3.4703x over previous
//
#include <hip/hip_runtime.h>
#include <math.h>

#define BATCH  8192
#define NNODES 500000
#define DIM    128
#define TDIM   64
#define KNB    32
#define KSEL   16

// bf16 weight pool element offsets
#define OFF_W1   0
#define OFF_W2   40960
#define OFF_WIH  57344
#define OFF_WHH  106496
#define OFF_WQ   155648
#define OFF_WV   172032
#define OFF_WO   196608
#define OFF_WM1  212992
#define OFF_WM2  245760
#define OFF_WKT  262144
#define CVT_TOT  286720

// prep kernel block ranges
#define NB_CVT  1120                  // CVT_TOT / 256 exactly
#define NB_WIN  (NB_CVT + 64)         // 16384 threads for winner scatter
#define NB_TOPK (NB_WIN + 32)         // 8192 threads for top-k

typedef float  f32x4  __attribute__((ext_vector_type(4)));
typedef __bf16 bf16x8 __attribute__((ext_vector_type(8)));
typedef short  s16x8  __attribute__((ext_vector_type(8)));

#define MFMA(a,b,c) __builtin_amdgcn_mfma_f32_16x16x32_bf16(a,b,c,0,0,0)

__device__ __forceinline__ float rcpf_(float x) { return __builtin_amdgcn_rcpf(x); }
__device__ __forceinline__ float fsigmoid(float x) { return rcpf_(1.f + __expf(-x)); }
__device__ __forceinline__ float ftanh(float x) {
    float e = __expf(2.f * x);
    return 1.f - 2.f * rcpf_(e + 1.f);
}
__device__ __forceinline__ unsigned short f2bf(float x) {
    unsigned u = __builtin_bit_cast(unsigned, x);
    unsigned r = (u + 0x7FFFu + ((u >> 16) & 1u)) >> 16;
    return (unsigned short)r;
}
__device__ __forceinline__ float bf2f(unsigned short u) {
    unsigned v = ((unsigned)u) << 16;
    return __builtin_bit_cast(float, v);
}
__device__ __forceinline__ bf16x8 ldfrag(const unsigned short* p) {
    s16x8 v = *(const s16x8*)p;
    return __builtin_bit_cast(bf16x8, v);
}
__device__ __forceinline__ uint2 pack4bf(float4 v) {
    uint2 pk;
    pk.x = (unsigned)f2bf(v.x) | ((unsigned)f2bf(v.y) << 16);
    pk.y = (unsigned)f2bf(v.z) | ((unsigned)f2bf(v.w) << 16);
    return pk;
}

// ---------------------------------------------------------------------------
// K_prep: [0,NB_CVT) weight->bf16 pool | [NB_CVT,NB_WIN) winner scatter |
//         [NB_WIN,NB_TOPK) temporal top-16-of-32.
// ---------------------------------------------------------------------------
__global__ __launch_bounds__(256) void k_prep(
    const float* __restrict__ sW1, const float* __restrict__ sW2,
    const float* __restrict__ sWih, const float* __restrict__ sWhh,
    const float* __restrict__ sWq, const float* __restrict__ sWv,
    const float* __restrict__ sWo, const float* __restrict__ sWm1,
    const float* __restrict__ sWm2, const float* __restrict__ sWk,
    unsigned short* __restrict__ pool,
    const int* __restrict__ src, const int* __restrict__ dst,
    int* __restrict__ winner,
    const float* __restrict__ ts,
    const int* __restrict__ nbr_ids, const float* __restrict__ nbr_ts,
    int* __restrict__ sel_id, float* __restrict__ sel_td, int* __restrict__ sel_mk)
{
    const int bid = blockIdx.x;
    const int tid = threadIdx.x;

    if (bid < NB_CVT) {
        int i = bid * 256 + tid;
        float v;
        if      (i < OFF_W2)  { v = sW1 [i - OFF_W1 ]; }
        else if (i < OFF_WIH) { v = sW2 [i - OFF_W2 ]; }
        else if (i < OFF_WHH) { v = sWih[i - OFF_WIH]; }
        else if (i < OFF_WQ)  { v = sWhh[i - OFF_WHH]; }
        else if (i < OFF_WV)  { v = sWq [i - OFF_WQ ]; }
        else if (i < OFF_WO)  { v = sWv [i - OFF_WV ]; }
        else if (i < OFF_WM1) { v = sWo [i - OFF_WO ]; }
        else if (i < OFF_WM2) { v = sWm1[i - OFF_WM1]; }
        else if (i < OFF_WKT) { v = sWm2[i - OFF_WM2]; }
        else {
            int j = i - OFF_WKT;           // h*12288 + c*64 + dh
            int h = j / 12288, rem = j % 12288;
            int c = rem >> 6, dh = rem & 63;
            v = sWk[(size_t)(h * 64 + dh) * 192 + c];
        }
        pool[i] = f2bf(v);
        return;
    }
    if (bid < NB_WIN) {
        int i = (bid - NB_CVT) * 256 + tid;
        if (i < 2 * BATCH) {
            int v = (i < BATCH) ? src[i] : dst[i - BATCH];
            atomicMax(&winner[v], i);
        }
        return;
    }
    {
        int b = (bid - NB_WIN) * 256 + tid;
        if (b >= BATCH) return;
        int   s = src[b];
        float t = ts[b];
        const int4*   ip4 = (const int4*)  (nbr_ids + (size_t)s * KNB);
        const float4* tp4 = (const float4*)(nbr_ts  + (size_t)s * KNB);
        float kt[KNB]; int kid[KNB];
        #pragma unroll
        for (int j4 = 0; j4 < 8; ++j4) {
            int4   id4 = ip4[j4];
            float4 nt4 = tp4[j4];
            int   ids[4] = { id4.x, id4.y, id4.z, id4.w };
            float nts[4] = { nt4.x, nt4.y, nt4.z, nt4.w };
            #pragma unroll
            for (int q = 0; q < 4; ++q) {
                int j = j4 * 4 + q;
                bool valid = (ids[q] >= 0) && (nts[q] < t + 1e-6f);
                kt[j]  = valid ? nts[q] : -1e30f;
                kid[j] = ids[q];
            }
        }
        unsigned picked = 0u;
        for (int sI = 0; sI < KSEL; ++sI) {
            float bv = -3.4e38f; int bj = 0; int bid2 = 0;
            #pragma unroll
            for (int j = 0; j < KNB; ++j) {
                bool avail = !((picked >> j) & 1u);
                if (avail && kt[j] > bv) { bv = kt[j]; bj = j; bid2 = kid[j]; }
            }
            picked |= (1u << bj);
            bool mk = bv > -1e29f;
            int id = mk ? (bid2 < 0 ? 0 : (bid2 > NNODES - 1 ? NNODES - 1 : bid2)) : 0;
            sel_id[b * KSEL + sI] = id;
            sel_td[b * KSEL + sI] = mk ? (t - bv) : 0.f;
            sel_mk[b * KSEL + sI] = mk ? 1 : 0;
        }
    }
}

// ---------------------------------------------------------------------------
// K1 (MFMA): message MLP + GRU. 64 rows/block, 8 waves (512 thr).
// Wave w owns output cols [w*16, w*16+16); 4 A-tiles per wave.
// ---------------------------------------------------------------------------
__global__ __launch_bounds__(512) void k1_mfma(
    const int* __restrict__ src, const int* __restrict__ dst, const float* __restrict__ ts,
    const float* __restrict__ memory, const float* __restrict__ last_update,
    const float* __restrict__ w_t, const float* __restrict__ b_t,
    const unsigned short* __restrict__ Wp,
    const float* __restrict__ b1, const float* __restrict__ b2,
    const float* __restrict__ bih, const float* __restrict__ bhh,
    float* __restrict__ new_mem)
{
    __shared__ unsigned short sxb[64][328];   // [self|oth|te] bf16, pad 8
    __shared__ unsigned short hb [64][136];   // h1 then msg
    __shared__ int   s_node[64];
    __shared__ int   s_oth [64];
    __shared__ float s_dt  [64];

    const unsigned short* W1b  = Wp + OFF_W1;
    const unsigned short* W2b  = Wp + OFF_W2;
    const unsigned short* Wihb = Wp + OFF_WIH;
    const unsigned short* Whhb = Wp + OFF_WHH;

    const int tid  = threadIdx.x;
    const int base = blockIdx.x * 64;

    if (tid < 64) {
        int gi = base + tid;
        int node, oth; float t;
        if (gi < BATCH) { node = src[gi];         oth = dst[gi];         t = ts[gi]; }
        else            { node = dst[gi - BATCH]; oth = src[gi - BATCH]; t = ts[gi - BATCH]; }
        s_node[tid] = node;
        s_oth[tid]  = oth;
        s_dt[tid]   = t - last_update[node];
    }
    __syncthreads();

    for (int idx = tid; idx < 64 * 32; idx += 512) {
        int r = idx >> 5, c4 = (idx & 31) << 2;
        float4 vs = *(const float4*)&memory[(size_t)s_node[r] * DIM + c4];
        float4 vo = *(const float4*)&memory[(size_t)s_oth[r]  * DIM + c4];
        *(uint2*)&sxb[r][c4]       = pack4bf(vs);
        *(uint2*)&sxb[r][128 + c4] = pack4bf(vo);
    }
    for (int idx = tid; idx < 64 * TDIM; idx += 512) {
        int r = idx >> 6, c = idx & 63;
        float f = s_dt[r] * w_t[c] + b_t[c];
        sxb[r][256 + c] = f2bf((c & 1) ? __cosf(f) : __sinf(f));
    }
    __syncthreads();

    const int w    = tid >> 6;        // 0..7
    const int l    = tid & 63;
    const int rowA = l & 15;
    const int kg   = l >> 4;
    const int n0   = w * 16;
    const int col  = l & 15;
    const int rgrp = l >> 4;

    // ---- stage 1: h1 = relu(x @ W1^T + b1), K=320 ---------------------------
    {
        f32x4 a0 = {0.f,0.f,0.f,0.f}, a1 = {0.f,0.f,0.f,0.f};
        f32x4 a2 = {0.f,0.f,0.f,0.f}, a3 = {0.f,0.f,0.f,0.f};
        #pragma unroll
        for (int kt = 0; kt < 10; ++kt) {
            int ko = kt * 32 + kg * 8;
            bf16x8 bfr = ldfrag(&W1b[(size_t)(n0 + rowA) * 320 + ko]);
            a0 = MFMA(ldfrag(&sxb[     rowA][ko]), bfr, a0);
            a1 = MFMA(ldfrag(&sxb[16 + rowA][ko]), bfr, a1);
            a2 = MFMA(ldfrag(&sxb[32 + rowA][ko]), bfr, a2);
            a3 = MFMA(ldfrag(&sxb[48 + rowA][ko]), bfr, a3);
        }
        float bb = b1[n0 + col];
        #pragma unroll
        for (int rgi = 0; rgi < 4; ++rgi) {
            int rb = rgrp * 4 + rgi;
            hb[rb     ][n0 + col] = f2bf(fmaxf(a0[rgi] + bb, 0.f));
            hb[rb + 16][n0 + col] = f2bf(fmaxf(a1[rgi] + bb, 0.f));
            hb[rb + 32][n0 + col] = f2bf(fmaxf(a2[rgi] + bb, 0.f));
            hb[rb + 48][n0 + col] = f2bf(fmaxf(a3[rgi] + bb, 0.f));
        }
    }
    __syncthreads();

    // ---- stage 2: msg = h1 @ W2^T + b2, K=128 -------------------------------
    {
        f32x4 m0 = {0.f,0.f,0.f,0.f}, m1 = {0.f,0.f,0.f,0.f};
        f32x4 m2 = {0.f,0.f,0.f,0.f}, m3 = {0.f,0.f,0.f,0.f};
        #pragma unroll
        for (int kt = 0; kt < 4; ++kt) {
            int ko = kt * 32 + kg * 8;
            bf16x8 bfr = ldfrag(&W2b[(size_t)(n0 + rowA) * 128 + ko]);
            m0 = MFMA(ldfrag(&hb[     rowA][ko]), bfr, m0);
            m1 = MFMA(ldfrag(&hb[16 + rowA][ko]), bfr, m1);
            m2 = MFMA(ldfrag(&hb[32 + rowA][ko]), bfr, m2);
            m3 = MFMA(ldfrag(&hb[48 + rowA][ko]), bfr, m3);
        }
        __syncthreads();   // all h1 reads done before overwrite
        float bb = b2[n0 + col];
        #pragma unroll
        for (int rgi = 0; rgi < 4; ++rgi) {
            int rb = rgrp * 4 + rgi;
            hb[rb     ][n0 + col] = f2bf(m0[rgi] + bb);
            hb[rb + 16][n0 + col] = f2bf(m1[rgi] + bb);
            hb[rb + 32][n0 + col] = f2bf(m2[rgi] + bb);
            hb[rb + 48][n0 + col] = f2bf(m3[rgi] + bb);
        }
    }
    __syncthreads();

    // ---- stage 3: GRU gates, one 16-col pass per wave, 4 A-tiles ------------
    {
        f32x4 g[6][4];
        #pragma unroll
        for (int gi_ = 0; gi_ < 6; ++gi_)
            #pragma unroll
            for (int ta = 0; ta < 4; ++ta) g[gi_][ta] = (f32x4){0.f,0.f,0.f,0.f};
        #pragma unroll
        for (int kt = 0; kt < 4; ++kt) {
            int ko = kt * 32 + kg * 8;
            int br = n0 + rowA;
            bf16x8 bir = ldfrag(&Wihb[(size_t)(      br) * 128 + ko]);
            bf16x8 biz = ldfrag(&Wihb[(size_t)(128 + br) * 128 + ko]);
            bf16x8 big = ldfrag(&Wihb[(size_t)(256 + br) * 128 + ko]);
            bf16x8 bhr = ldfrag(&Whhb[(size_t)(      br) * 128 + ko]);
            bf16x8 bhz = ldfrag(&Whhb[(size_t)(128 + br) * 128 + ko]);
            bf16x8 bhg = ldfrag(&Whhb[(size_t)(256 + br) * 128 + ko]);
            #pragma unroll
            for (int ta = 0; ta < 4; ++ta) {
                bf16x8 am = ldfrag(&hb [ta * 16 + rowA][ko]);
                bf16x8 ah = ldfrag(&sxb[ta * 16 + rowA][ko]);
                g[0][ta] = MFMA(am, bir, g[0][ta]);
                g[1][ta] = MFMA(am, biz, g[1][ta]);
                g[2][ta] = MFMA(am, big, g[2][ta]);
                g[3][ta] = MFMA(ah, bhr, g[3][ta]);
                g[4][ta] = MFMA(ah, bhz, g[4][ta]);
                g[5][ta] = MFMA(ah, bhg, g[5][ta]);
            }
        }
        const int d = n0 + col;
        float bir = bih[d], biz = bih[128 + d], big = bih[256 + d];
        float bhr = bhh[d], bhz = bhh[128 + d], bhg = bhh[256 + d];
        #pragma unroll
        for (int ta = 0; ta < 4; ++ta)
            #pragma unroll
            for (int rgi = 0; rgi < 4; ++rgi) {
                int rr = ta * 16 + rgrp * 4 + rgi;
                float rv = fsigmoid((g[0][ta][rgi] + bir) + (g[3][ta][rgi] + bhr));
                float zv = fsigmoid((g[1][ta][rgi] + biz) + (g[4][ta][rgi] + bhz));
                float gv = ftanh((g[2][ta][rgi] + big) + rv * (g[5][ta][rgi] + bhg));
                float selfv = bf2f(sxb[rr][d]);
                new_mem[(size_t)(base + rr) * DIM + d] = (1.f - zv) * gv + zv * selfv;
            }
    }
}

// ---------------------------------------------------------------------------
// K3 fused: 32 rows/block, 8 waves (512 thr). Q/u proj (MFMA) -> per-wave
// gather+scores+softmax+kvbar (wave-private, reg-prefetch) -> Wv/Wo/Wm1/Wm2
// MFMA back-end + LayerNorm.
// ---------------------------------------------------------------------------
__global__ __launch_bounds__(512) void k3_fused(
    const int* __restrict__ src,
    const float* __restrict__ memory, const float* __restrict__ new_mem,
    const int* __restrict__ winner,
    const int* __restrict__ sel_id, const float* __restrict__ sel_td,
    const int* __restrict__ sel_mk,
    const float* __restrict__ w_ta, const float* __restrict__ b_ta,
    const unsigned short* __restrict__ Wp,
    const float* __restrict__ bq, const float* __restrict__ bk,
    const float* __restrict__ bv, const float* __restrict__ bo,
    const float* __restrict__ bm1, const float* __restrict__ bm2,
    const float* __restrict__ ln_g, const float* __restrict__ ln_b,
    float* __restrict__ out)
{
    __shared__ unsigned short s_nfB[32][136];     // node features bf16
    __shared__ unsigned short s_qB [32][136];     // Q bf16
    __shared__ unsigned short s_u  [32][2][200];  // u = Wk_h^T Q_h, bf16
    __shared__ unsigned short s_kvb[32][2][200];  // kvbar bf16
    __shared__ unsigned long long s_pool64[6400]; // 51200B: kv staging / phase-B bufs
    __shared__ const float* s_nptr[32][16];
    __shared__ float s_td [32][16];
    __shared__ int   s_mk [32][16];
    __shared__ float s_qb [32][2];
    __shared__ float s_satt[32][2];
    __shared__ float s_at [8][2][16];
    __shared__ const float* s_ptr[32];

    const unsigned short* Wqb  = Wp + OFF_WQ;
    const unsigned short* WkTb = Wp + OFF_WKT;
    const unsigned short* Wvb  = Wp + OFF_WV;
    const unsigned short* Wob  = Wp + OFF_WO;
    const unsigned short* Wm1b = Wp + OFF_WM1;
    const unsigned short* Wm2b = Wp + OFF_WM2;

    const int tid  = threadIdx.x;
    const int base = blockIdx.x * 32;

    // ---- stage pointers + per-row neighbor metadata -------------------------
    if (tid < 32) {
        int v = src[base + tid];
        int wv = winner[v];
        s_ptr[tid] = (wv >= 0) ? (new_mem + (size_t)wv * DIM)
                               : (memory  + (size_t)v  * DIM);
    }
    {
        int r = tid >> 4, n = tid & 15;        // 512 threads = 32 rows x 16
        int id = sel_id[(base + r) * KSEL + n];
        int wi = winner[id];
        s_nptr[r][n] = (wi >= 0) ? (new_mem + (size_t)wi * DIM)
                                 : (memory  + (size_t)id * DIM);
        s_td[r][n] = sel_td[(base + r) * KSEL + n];
        s_mk[r][n] = sel_mk[(base + r) * KSEL + n];
    }
    __syncthreads();

    // ---- gather node features -> s_nfB --------------------------------------
    for (int idx = tid; idx < 32 * 32; idx += 512) {
        int r = idx >> 5, c4 = (idx & 31) << 2;
        float4 v = *(const float4*)&s_ptr[r][c4];
        *(uint2*)&s_nfB[r][c4] = pack4bf(v);
    }
    __syncthreads();

    const int w    = tid >> 6;        // 0..7
    const int l    = tid & 63;
    const int rowA = l & 15;
    const int kg   = l >> 4;
    const int col  = l & 15;
    const int rgrp = l >> 4;

    // ---- phase 0a: Q = nf @ Wq^T + bq (wave w: cols w*16..w*16+16) ----------
    {
        const int n0 = w * 16;
        f32x4 q0 = {0.f,0.f,0.f,0.f}, q1 = {0.f,0.f,0.f,0.f};
        #pragma unroll
        for (int kt = 0; kt < 4; ++kt) {
            int ko = kt * 32 + kg * 8;
            bf16x8 bfr = ldfrag(&Wqb[(size_t)(n0 + rowA) * 128 + ko]);
            q0 = MFMA(ldfrag(&s_nfB[     rowA][ko]), bfr, q0);
            q1 = MFMA(ldfrag(&s_nfB[16 + rowA][ko]), bfr, q1);
        }
        float bb = bq[n0 + col];
        #pragma unroll
        for (int rgi = 0; rgi < 4; ++rgi) {
            int rb = rgrp * 4 + rgi;
            s_qB[rb     ][n0 + col] = f2bf(q0[rgi] + bb);
            s_qB[rb + 16][n0 + col] = f2bf(q1[rgi] + bb);
        }
    }
    __syncthreads();

    // ---- phase 0b: qb[r][h] = Q_h . bk_h  (256 threads) ---------------------
    if (tid < 256) {
        int r = tid >> 3, rem = tid & 7, h = rem >> 2, p = rem & 3;
        float part = 0.f;
        #pragma unroll
        for (int j = 0; j < 16; ++j) {
            int dd = h * 64 + p * 16 + j;
            part += bf2f(s_qB[r][dd]) * bk[dd];
        }
        part += __shfl_xor(part, 1);
        part += __shfl_xor(part, 2);
        if (p == 0) s_qb[r][h] = part;
    }

    // ---- phase 0c: u = Wk_h^T Q_h (wave w: head w>>2, cols (w&3)*48) --------
    {
        const int h  = w >> 2;
        const int cb = (w & 3) * 48;
        f32x4 u[3][2];
        #pragma unroll
        for (int ct = 0; ct < 3; ++ct)
            #pragma unroll
            for (int ta = 0; ta < 2; ++ta) u[ct][ta] = (f32x4){0.f,0.f,0.f,0.f};
        #pragma unroll
        for (int kt = 0; kt < 2; ++kt) {
            int ko = kt * 32 + kg * 8;
            bf16x8 bfr[3];
            #pragma unroll
            for (int ct = 0; ct < 3; ++ct)
                bfr[ct] = ldfrag(&WkTb[(size_t)h * 12288 + (size_t)(cb + ct * 16 + rowA) * 64 + ko]);
            #pragma unroll
            for (int ta = 0; ta < 2; ++ta) {
                bf16x8 av = ldfrag(&s_qB[ta * 16 + rowA][h * 64 + ko]);
                #pragma unroll
                for (int ct = 0; ct < 3; ++ct)
                    u[ct][ta] = MFMA(av, bfr[ct], u[ct][ta]);
            }
        }
        #pragma unroll
        for (int ct = 0; ct < 3; ++ct)
            #pragma unroll
            for (int ta = 0; ta < 2; ++ta)
                #pragma unroll
                for (int rgi = 0; rgi < 4; ++rgi) {
                    int rr = ta * 16 + rgrp * 4 + rgi;
                    s_u[rr][h][cb + ct * 16 + col] = f2bf(u[ct][ta][rgi]);
                }
    }
    __syncthreads();

    // ---- phase A: per-wave 4 rows, wave-private, reg-prefetched gather ------
    {
        unsigned short (*kvbuf)[16][200] = (unsigned short (*)[16][200])s_pool64;
        float wt = w_ta[l], bt = b_ta[l];
        const int pfn = l >> 5;            // this lane's neighbor parity
        const int pfc = (l & 31) << 2;     // this lane's 4-col base

        float4 pf[8];
        {
            const int r = w * 4;
            #pragma unroll
            for (int it = 0; it < 8; ++it)
                pf[it] = *(const float4*)&s_nptr[r][it * 2 + pfn][pfc];
        }

        for (int rr = 0; rr < 4; ++rr) {
            const int r = w * 4 + rr;
            // write prefetched kv rows to LDS (bf16, packed)
            #pragma unroll
            for (int it = 0; it < 8; ++it)
                *(uint2*)&kvbuf[w][it * 2 + pfn][pfc] = pack4bf(pf[it]);
            // time encoding
            #pragma unroll
            for (int n = 0; n < 16; ++n) {
                float f = s_td[r][n] * wt + bt;
                kvbuf[w][n][128 + l] = f2bf((l & 1) ? __cosf(f) : __sinf(f));
            }
            // issue next row's gather now; latency hides under scores/kvbar
            if (rr < 3) {
                const int rn = r + 1;
                #pragma unroll
                for (int it = 0; it < 8; ++it)
                    pf[it] = *(const float4*)&s_nptr[rn][it * 2 + pfn][pfc];
            }
            __builtin_amdgcn_wave_barrier();

            // scores + masked softmax (wave-internal)
            {
                int h = (l >> 4) & 1, n = l & 15, half = l >> 5;
                float acc = (half == 0) ? s_qb[r][h] : 0.f;
                const unsigned short* kvrow = &kvbuf[w][n][half * 96];
                const unsigned short* urow  = &s_u[r][h][half * 96];
                #pragma unroll
                for (int k = 0; k < 96; k += 8) {
                    s16x8 kv8 = *(const s16x8*)&kvrow[k];
                    s16x8 u8  = *(const s16x8*)&urow[k];
                    #pragma unroll
                    for (int j = 0; j < 8; ++j)
                        acc += bf2f((unsigned short)kv8[j]) * bf2f((unsigned short)u8[j]);
                }
                acc += __shfl_xor(acc, 32);
                int mk = s_mk[r][n];
                float s = mk ? acc * 0.125f : -INFINITY;
                float mx = s;
                #pragma unroll
                for (int m = 1; m < 16; m <<= 1) mx = fmaxf(mx, __shfl_xor(mx, m));
                float p = (mk && mx > -1e37f) ? __expf(s - mx) : 0.f;
                float den = p;
                #pragma unroll
                for (int m = 1; m < 16; m <<= 1) den += __shfl_xor(den, m);
                float a = (den > 0.f) ? (p * rcpf_(den)) : 0.f;
                if (l < 32) s_at[w][h][n] = a;
                if (l == 0 || l == 16) s_satt[r][h] = (den > 0.f) ? 1.f : 0.f;
            }
            __builtin_amdgcn_wave_barrier();

            // kvbar[h][c] = sum_n at[h][n] * kv[n][c]  -> s_kvb (bf16)
            #pragma unroll
            for (int i = 0; i < 3; ++i) {
                int c = i * 64 + l;
                float k0 = 0.f, k1 = 0.f;
                #pragma unroll
                for (int n = 0; n < 16; ++n) {
                    float v = bf2f(kvbuf[w][n][c]);
                    k0 += s_at[w][0][n] * v;
                    k1 += s_at[w][1][n] * v;
                }
                s_kvb[r][0][c] = f2bf(k0);
                s_kvb[r][1][c] = f2bf(k1);
            }
            __builtin_amdgcn_wave_barrier();
        }
    }
    __syncthreads();

    // ---- phase B: MFMA back-end (pool aliased: kv staging is dead) ----------
    unsigned short (*s_aoB)[136] = (unsigned short (*)[136])s_pool64;
    unsigned short (*s_oB )[136] = (unsigned short (*)[136])((char*)s_pool64 + 8704);
    unsigned short (*s_h1B)[136] = (unsigned short (*)[136])((char*)s_pool64 + 17408);
    float          (*s_h2 )[128] = (float          (*)[128])((char*)s_pool64 + 26112);

    // out = Wv_h @ kvbar_h + satt_h*bv : wave w -> head w>>2, cols (w&3)*16
    {
        const int h  = w >> 2;
        const int c0 = (w & 3) * 16;
        f32x4 o0 = {0.f,0.f,0.f,0.f}, o1 = {0.f,0.f,0.f,0.f};
        #pragma unroll
        for (int kt = 0; kt < 6; ++kt) {
            int ko = kt * 32 + kg * 8;
            bf16x8 bfr = ldfrag(&Wvb[(size_t)(h * 64 + c0 + rowA) * 192 + ko]);
            o0 = MFMA(ldfrag(&s_kvb[     rowA][h][ko]), bfr, o0);
            o1 = MFMA(ldfrag(&s_kvb[16 + rowA][h][ko]), bfr, o1);
        }
        int d0 = h * 64 + c0 + col;
        float bv0 = bv[d0];
        #pragma unroll
        for (int rgi = 0; rgi < 4; ++rgi) {
            int rb = rgrp * 4 + rgi;
            s_oB[rb     ][d0] = f2bf(o0[rgi] + s_satt[rb     ][h] * bv0);
            s_oB[rb + 16][d0] = f2bf(o1[rgi] + s_satt[rb + 16][h] * bv0);
        }
    }
    __syncthreads();

    // ao = Wo @ out + bo
    {
        const int n0 = w * 16;
        f32x4 a0 = {0.f,0.f,0.f,0.f}, a1 = {0.f,0.f,0.f,0.f};
        #pragma unroll
        for (int kt = 0; kt < 4; ++kt) {
            int ko = kt * 32 + kg * 8;
            bf16x8 bfr = ldfrag(&Wob[(size_t)(n0 + rowA) * 128 + ko]);
            a0 = MFMA(ldfrag(&s_oB[     rowA][ko]), bfr, a0);
            a1 = MFMA(ldfrag(&s_oB[16 + rowA][ko]), bfr, a1);
        }
        float bb = bo[n0 + col];
        #pragma unroll
        for (int rgi = 0; rgi < 4; ++rgi) {
            int rb = rgrp * 4 + rgi;
            s_aoB[rb     ][n0 + col] = f2bf(a0[rgi] + bb);
            s_aoB[rb + 16][n0 + col] = f2bf(a1[rgi] + bb);
        }
    }
    __syncthreads();

    // h1 = relu(Wm1 @ [ao|nf] + bm1), K=256 (kt 0..3: ao, kt 4..7: nf)
    {
        const int n0 = w * 16;
        f32x4 a0 = {0.f,0.f,0.f,0.f}, a1 = {0.f,0.f,0.f,0.f};
        #pragma unroll
        for (int kt = 0; kt < 8; ++kt) {
            int ko = kt * 32 + kg * 8;
            bf16x8 av0 = (kt < 4) ? ldfrag(&s_aoB[     rowA][ko])
                                  : ldfrag(&s_nfB[     rowA][ko - 128]);
            bf16x8 av1 = (kt < 4) ? ldfrag(&s_aoB[16 + rowA][ko])
                                  : ldfrag(&s_nfB[16 + rowA][ko - 128]);
            bf16x8 bfr = ldfrag(&Wm1b[(size_t)(n0 + rowA) * 256 + ko]);
            a0 = MFMA(av0, bfr, a0);
            a1 = MFMA(av1, bfr, a1);
        }
        float bb = bm1[n0 + col];
        #pragma unroll
        for (int rgi = 0; rgi < 4; ++rgi) {
            int rb = rgrp * 4 + rgi;
            s_h1B[rb     ][n0 + col] = f2bf(fmaxf(a0[rgi] + bb, 0.f));
            s_h1B[rb + 16][n0 + col] = f2bf(fmaxf(a1[rgi] + bb, 0.f));
        }
    }
    __syncthreads();

    // h2 = Wm2 @ h1 + bm2 -> f32
    {
        const int n0 = w * 16;
        f32x4 a0 = {0.f,0.f,0.f,0.f}, a1 = {0.f,0.f,0.f,0.f};
        #pragma unroll
        for (int kt = 0; kt < 4; ++kt) {
            int ko = kt * 32 + kg * 8;
            bf16x8 bfr = ldfrag(&Wm2b[(size_t)(n0 + rowA) * 128 + ko]);
            a0 = MFMA(ldfrag(&s_h1B[     rowA][ko]), bfr, a0);
            a1 = MFMA(ldfrag(&s_h1B[16 + rowA][ko]), bfr, a1);
        }
        float bb = bm2[n0 + col];
        #pragma unroll
        for (int rgi = 0; rgi < 4; ++rgi) {
            int rb = rgrp * 4 + rgi;
            s_h2[rb     ][n0 + col] = a0[rgi] + bb;
            s_h2[rb + 16][n0 + col] = a1[rgi] + bb;
        }
    }
    __syncthreads();

    // LayerNorm: wave w -> rows w*4 .. w*4+3
    {
        float lg0 = ln_g[l], lg1 = ln_g[64 + l];
        float lb0 = ln_b[l], lb1 = ln_b[64 + l];
        #pragma unroll
        for (int i = 0; i < 4; ++i) {
            int r = w * 4 + i;
            float v0 = s_h2[r][l], v1 = s_h2[r][64 + l];
            float sum = v0 + v1;
            #pragma unroll
            for (int m = 1; m < 64; m <<= 1) sum += __shfl_xor(sum, m);
            float mean = sum * (1.f / 128.f);
            float e0 = v0 - mean, e1 = v1 - mean;
            float sq = e0 * e0 + e1 * e1;
            #pragma unroll
            for (int m = 1; m < 64; m <<= 1) sq += __shfl_xor(sq, m);
            float inv = rsqrtf(sq * (1.f / 128.f) + 1e-5f);
            out[(size_t)(base + r) * DIM + l]      = e0 * inv * lg0 + lb0;
            out[(size_t)(base + r) * DIM + 64 + l] = e1 * inv * lg1 + lb1;
        }
    }
}

// ---------------------------------------------------------------------------
extern "C" void kernel_launch(void* const* d_in, const int* in_sizes, int n_in,
                              void* d_out, int out_size, void* d_ws, size_t ws_size,
                              hipStream_t stream) {
    const int*   src         = (const int*)  d_in[0];
    const int*   dst         = (const int*)  d_in[1];
    const float* ts          = (const float*)d_in[2];
    const int*   nbr_ids     = (const int*)  d_in[3];
    const float* nbr_ts      = (const float*)d_in[4];
    const float* memory      = (const float*)d_in[5];
    const float* last_update = (const float*)d_in[6];
    const float* w_t_msg     = (const float*)d_in[7];
    const float* b_t_msg     = (const float*)d_in[8];
    const float* W_msg1      = (const float*)d_in[9];
    const float* b_msg1      = (const float*)d_in[10];
    const float* W_msg2      = (const float*)d_in[11];
    const float* b_msg2      = (const float*)d_in[12];
    const float* W_ih        = (const float*)d_in[13];
    const float* b_ih        = (const float*)d_in[14];
    const float* W_hh        = (const float*)d_in[15];
    const float* b_hh        = (const float*)d_in[16];
    const float* w_t_att     = (const float*)d_in[17];
    const float* b_t_att     = (const float*)d_in[18];
    const float* Wq          = (const float*)d_in[19];
    const float* bq          = (const float*)d_in[20];
    const float* Wk          = (const float*)d_in[21];
    const float* bk          = (const float*)d_in[22];
    const float* Wv          = (const float*)d_in[23];
    const float* bv          = (const float*)d_in[24];
    const float* Wo          = (const float*)d_in[25];
    const float* bo          = (const float*)d_in[26];
    const float* Wm1         = (const float*)d_in[27];
    const float* bm1         = (const float*)d_in[28];
    const float* Wm2         = (const float*)d_in[29];
    const float* bm2         = (const float*)d_in[30];
    const float* ln_g        = (const float*)d_in[31];
    const float* ln_b        = (const float*)d_in[32];
    float* out = (float*)d_out;

    char* ws = (char*)d_ws;
    size_t off = 0;
    float* new_mem = (float*)(ws + off); off += (size_t)2 * BATCH * DIM * 4;   // 8 MiB
    int*   winner  = (int*)  (ws + off); off += 2097152;                       // 2 MiB
    int*   sel_id  = (int*)  (ws + off); off += (size_t)BATCH * KSEL * 4;
    float* sel_td  = (float*)(ws + off); off += (size_t)BATCH * KSEL * 4;
    int*   sel_mk  = (int*)  (ws + off); off += (size_t)BATCH * KSEL * 4;
    unsigned short* Wpool = (unsigned short*)(ws + off); off += (size_t)CVT_TOT * 2;

    hipMemsetAsync(winner, 0xFF, NNODES * sizeof(int), stream);
    k_prep<<<NB_TOPK, 256, 0, stream>>>(
        W_msg1, W_msg2, W_ih, W_hh, Wq, Wv, Wo, Wm1, Wm2, Wk, Wpool,
        src, dst, winner, ts, nbr_ids, nbr_ts, sel_id, sel_td, sel_mk);
    k1_mfma<<<(2 * BATCH) / 64, 512, 0, stream>>>(
        src, dst, ts, memory, last_update,
        w_t_msg, b_t_msg, Wpool, b_msg1, b_msg2, b_ih, b_hh, new_mem);
    k3_fused<<<BATCH / 32, 512, 0, stream>>>(
        src, memory, new_mem, winner, sel_id, sel_td, sel_mk,
        w_t_att, b_t_att, Wpool, bq, bk, bv, bo, bm1, bm2, ln_g, ln_b, out);
}

// Round 11
// 72.256 us; speedup vs baseline: 3.5940x; 1.0357x over previous
//
#include <hip/hip_runtime.h>
#include <math.h>

#define BATCH  8192
#define NNODES 500000
#define DIM    128
#define TDIM   64
#define KNB    32
#define KSEL   16

// bf16 weight pool element offsets
#define OFF_W1   0
#define OFF_W2   40960
#define OFF_WIH  57344
#define OFF_WHH  106496
#define OFF_WQ   155648
#define OFF_WV   172032
#define OFF_WO   196608
#define OFF_WM1  212992
#define OFF_WM2  245760
#define OFF_WKT  262144
#define CVT_TOT  286720

#define NB_CVT  1120                  // CVT_TOT / 256 exactly

typedef float  f32x4  __attribute__((ext_vector_type(4)));
typedef __bf16 bf16x8 __attribute__((ext_vector_type(8)));
typedef short  s16x8  __attribute__((ext_vector_type(8)));

#define MFMA(a,b,c) __builtin_amdgcn_mfma_f32_16x16x32_bf16(a,b,c,0,0,0)

__device__ __forceinline__ float rcpf_(float x) { return __builtin_amdgcn_rcpf(x); }
__device__ __forceinline__ float fsigmoid(float x) { return rcpf_(1.f + __expf(-x)); }
__device__ __forceinline__ float ftanh(float x) {
    float e = __expf(2.f * x);
    return 1.f - 2.f * rcpf_(e + 1.f);
}
__device__ __forceinline__ unsigned short f2bf(float x) {
    unsigned u = __builtin_bit_cast(unsigned, x);
    unsigned r = (u + 0x7FFFu + ((u >> 16) & 1u)) >> 16;
    return (unsigned short)r;
}
__device__ __forceinline__ float bf2f(unsigned short u) {
    unsigned v = ((unsigned)u) << 16;
    return __builtin_bit_cast(float, v);
}
__device__ __forceinline__ bf16x8 ldfrag(const unsigned short* p) {
    s16x8 v = *(const s16x8*)p;
    return __builtin_bit_cast(bf16x8, v);
}
__device__ __forceinline__ uint2 pack4bf(float4 v) {
    uint2 pk;
    pk.x = (unsigned)f2bf(v.x) | ((unsigned)f2bf(v.y) << 16);
    pk.y = (unsigned)f2bf(v.z) | ((unsigned)f2bf(v.w) << 16);
    return pk;
}

// ---------------------------------------------------------------------------
// K_prep: weight->bf16 pool conversion + winner-array clear (grid-stride).
// Winner scatter and top-k moved into k1's prelude (consumed only by k3).
// ---------------------------------------------------------------------------
__global__ __launch_bounds__(256) void k_prep(
    const float* __restrict__ sW1, const float* __restrict__ sW2,
    const float* __restrict__ sWih, const float* __restrict__ sWhh,
    const float* __restrict__ sWq, const float* __restrict__ sWv,
    const float* __restrict__ sWo, const float* __restrict__ sWm1,
    const float* __restrict__ sWm2, const float* __restrict__ sWk,
    unsigned short* __restrict__ pool,
    int* __restrict__ winner)
{
    const int i = blockIdx.x * 256 + threadIdx.x;     // < CVT_TOT
    {
        float v;
        if      (i < OFF_W2)  { v = sW1 [i - OFF_W1 ]; }
        else if (i < OFF_WIH) { v = sW2 [i - OFF_W2 ]; }
        else if (i < OFF_WHH) { v = sWih[i - OFF_WIH]; }
        else if (i < OFF_WQ)  { v = sWhh[i - OFF_WHH]; }
        else if (i < OFF_WV)  { v = sWq [i - OFF_WQ ]; }
        else if (i < OFF_WO)  { v = sWv [i - OFF_WV ]; }
        else if (i < OFF_WM1) { v = sWo [i - OFF_WO ]; }
        else if (i < OFF_WM2) { v = sWm1[i - OFF_WM1]; }
        else if (i < OFF_WKT) { v = sWm2[i - OFF_WM2]; }
        else {
            int j = i - OFF_WKT;           // h*12288 + c*64 + dh
            int h = j / 12288, rem = j % 12288;
            int c = rem >> 6, dh = rem & 63;
            v = sWk[(size_t)(h * 64 + dh) * 192 + c];
        }
        pool[i] = f2bf(v);
    }
    // clear winner (scatter happens next dispatch, in k1's prelude)
    for (int j = i; j < NNODES; j += NB_CVT * 256) winner[j] = -1;
}

// ---------------------------------------------------------------------------
// K1 (MFMA): prelude {winner scatter + top-k} then message MLP + GRU.
// 64 rows/block, 8 waves (512 thr). Wave w owns output cols [w*16, w*16+16).
// ---------------------------------------------------------------------------
__global__ __launch_bounds__(512) void k1_mfma(
    const int* __restrict__ src, const int* __restrict__ dst, const float* __restrict__ ts,
    const float* __restrict__ memory, const float* __restrict__ last_update,
    const float* __restrict__ w_t, const float* __restrict__ b_t,
    const unsigned short* __restrict__ Wp,
    const float* __restrict__ b1, const float* __restrict__ b2,
    const float* __restrict__ bih, const float* __restrict__ bhh,
    float* __restrict__ new_mem,
    int* __restrict__ winner,
    const int* __restrict__ nbr_ids, const float* __restrict__ nbr_ts,
    int* __restrict__ sel_id, float* __restrict__ sel_td, int* __restrict__ sel_mk)
{
    __shared__ unsigned short sxb[64][328];   // [self|oth|te] bf16, pad 8
    __shared__ unsigned short hb [64][136];   // h1 then msg
    __shared__ int   s_node[64];
    __shared__ int   s_oth [64];
    __shared__ float s_dt  [64];

    const unsigned short* W1b  = Wp + OFF_W1;
    const unsigned short* W2b  = Wp + OFF_W2;
    const unsigned short* Wihb = Wp + OFF_WIH;
    const unsigned short* Whhb = Wp + OFF_WHH;

    const int tid  = threadIdx.x;
    const int bid  = blockIdx.x;
    const int base = bid * 64;

    // ---- prelude: winner scatter (64/block) + top-k (32 rows/block) ---------
    // Outputs consumed only by k3 (next dispatch); no block ordering needed.
    if (tid < 64) {
        int i = bid * 64 + tid;
        int v = (i < BATCH) ? src[i] : dst[i - BATCH];
        atomicMax(&winner[v], i);
    } else if (tid < 96) {
        int b = bid * 32 + (tid - 64);
        int   s = src[b];
        float t = ts[b];
        const int4*   ip4 = (const int4*)  (nbr_ids + (size_t)s * KNB);
        const float4* tp4 = (const float4*)(nbr_ts  + (size_t)s * KNB);
        float kt[KNB]; int kid[KNB];
        #pragma unroll
        for (int j4 = 0; j4 < 8; ++j4) {
            int4   id4 = ip4[j4];
            float4 nt4 = tp4[j4];
            int   ids[4] = { id4.x, id4.y, id4.z, id4.w };
            float nts[4] = { nt4.x, nt4.y, nt4.z, nt4.w };
            #pragma unroll
            for (int q = 0; q < 4; ++q) {
                int j = j4 * 4 + q;
                bool valid = (ids[q] >= 0) && (nts[q] < t + 1e-6f);
                kt[j]  = valid ? nts[q] : -1e30f;
                kid[j] = ids[q];
            }
        }
        unsigned picked = 0u;
        for (int sI = 0; sI < KSEL; ++sI) {
            float bv = -3.4e38f; int bj = 0; int bid2 = 0;
            #pragma unroll
            for (int j = 0; j < KNB; ++j) {
                bool avail = !((picked >> j) & 1u);
                if (avail && kt[j] > bv) { bv = kt[j]; bj = j; bid2 = kid[j]; }
            }
            picked |= (1u << bj);
            bool mk = bv > -1e29f;
            int id = mk ? (bid2 < 0 ? 0 : (bid2 > NNODES - 1 ? NNODES - 1 : bid2)) : 0;
            sel_id[b * KSEL + sI] = id;
            sel_td[b * KSEL + sI] = mk ? (t - bv) : 0.f;
            sel_mk[b * KSEL + sI] = mk ? 1 : 0;
        }
    }

    // ---- main k1 body -------------------------------------------------------
    if (tid < 64) {
        int gi = base + tid;
        int node, oth; float t;
        if (gi < BATCH) { node = src[gi];         oth = dst[gi];         t = ts[gi]; }
        else            { node = dst[gi - BATCH]; oth = src[gi - BATCH]; t = ts[gi - BATCH]; }
        s_node[tid] = node;
        s_oth[tid]  = oth;
        s_dt[tid]   = t - last_update[node];
    }
    __syncthreads();

    for (int idx = tid; idx < 64 * 32; idx += 512) {
        int r = idx >> 5, c4 = (idx & 31) << 2;
        float4 vs = *(const float4*)&memory[(size_t)s_node[r] * DIM + c4];
        float4 vo = *(const float4*)&memory[(size_t)s_oth[r]  * DIM + c4];
        *(uint2*)&sxb[r][c4]       = pack4bf(vs);
        *(uint2*)&sxb[r][128 + c4] = pack4bf(vo);
    }
    for (int idx = tid; idx < 64 * TDIM; idx += 512) {
        int r = idx >> 6, c = idx & 63;
        float f = s_dt[r] * w_t[c] + b_t[c];
        sxb[r][256 + c] = f2bf((c & 1) ? __cosf(f) : __sinf(f));
    }
    __syncthreads();

    const int w    = tid >> 6;        // 0..7
    const int l    = tid & 63;
    const int rowA = l & 15;
    const int kg   = l >> 4;
    const int n0   = w * 16;
    const int col  = l & 15;
    const int rgrp = l >> 4;

    // ---- stage 1: h1 = relu(x @ W1^T + b1), K=320 ---------------------------
    {
        f32x4 a0 = {0.f,0.f,0.f,0.f}, a1 = {0.f,0.f,0.f,0.f};
        f32x4 a2 = {0.f,0.f,0.f,0.f}, a3 = {0.f,0.f,0.f,0.f};
        #pragma unroll
        for (int kt = 0; kt < 10; ++kt) {
            int ko = kt * 32 + kg * 8;
            bf16x8 bfr = ldfrag(&W1b[(size_t)(n0 + rowA) * 320 + ko]);
            a0 = MFMA(ldfrag(&sxb[     rowA][ko]), bfr, a0);
            a1 = MFMA(ldfrag(&sxb[16 + rowA][ko]), bfr, a1);
            a2 = MFMA(ldfrag(&sxb[32 + rowA][ko]), bfr, a2);
            a3 = MFMA(ldfrag(&sxb[48 + rowA][ko]), bfr, a3);
        }
        float bb = b1[n0 + col];
        #pragma unroll
        for (int rgi = 0; rgi < 4; ++rgi) {
            int rb = rgrp * 4 + rgi;
            hb[rb     ][n0 + col] = f2bf(fmaxf(a0[rgi] + bb, 0.f));
            hb[rb + 16][n0 + col] = f2bf(fmaxf(a1[rgi] + bb, 0.f));
            hb[rb + 32][n0 + col] = f2bf(fmaxf(a2[rgi] + bb, 0.f));
            hb[rb + 48][n0 + col] = f2bf(fmaxf(a3[rgi] + bb, 0.f));
        }
    }
    __syncthreads();

    // ---- stage 2: msg = h1 @ W2^T + b2, K=128 -------------------------------
    {
        f32x4 m0 = {0.f,0.f,0.f,0.f}, m1 = {0.f,0.f,0.f,0.f};
        f32x4 m2 = {0.f,0.f,0.f,0.f}, m3 = {0.f,0.f,0.f,0.f};
        #pragma unroll
        for (int kt = 0; kt < 4; ++kt) {
            int ko = kt * 32 + kg * 8;
            bf16x8 bfr = ldfrag(&W2b[(size_t)(n0 + rowA) * 128 + ko]);
            m0 = MFMA(ldfrag(&hb[     rowA][ko]), bfr, m0);
            m1 = MFMA(ldfrag(&hb[16 + rowA][ko]), bfr, m1);
            m2 = MFMA(ldfrag(&hb[32 + rowA][ko]), bfr, m2);
            m3 = MFMA(ldfrag(&hb[48 + rowA][ko]), bfr, m3);
        }
        __syncthreads();   // all h1 reads done before overwrite
        float bb = b2[n0 + col];
        #pragma unroll
        for (int rgi = 0; rgi < 4; ++rgi) {
            int rb = rgrp * 4 + rgi;
            hb[rb     ][n0 + col] = f2bf(m0[rgi] + bb);
            hb[rb + 16][n0 + col] = f2bf(m1[rgi] + bb);
            hb[rb + 32][n0 + col] = f2bf(m2[rgi] + bb);
            hb[rb + 48][n0 + col] = f2bf(m3[rgi] + bb);
        }
    }
    __syncthreads();

    // ---- stage 3: GRU gates, one 16-col pass per wave, 4 A-tiles ------------
    {
        f32x4 g[6][4];
        #pragma unroll
        for (int gi_ = 0; gi_ < 6; ++gi_)
            #pragma unroll
            for (int ta = 0; ta < 4; ++ta) g[gi_][ta] = (f32x4){0.f,0.f,0.f,0.f};
        #pragma unroll
        for (int kt = 0; kt < 4; ++kt) {
            int ko = kt * 32 + kg * 8;
            int br = n0 + rowA;
            bf16x8 bir = ldfrag(&Wihb[(size_t)(      br) * 128 + ko]);
            bf16x8 biz = ldfrag(&Wihb[(size_t)(128 + br) * 128 + ko]);
            bf16x8 big = ldfrag(&Wihb[(size_t)(256 + br) * 128 + ko]);
            bf16x8 bhr = ldfrag(&Whhb[(size_t)(      br) * 128 + ko]);
            bf16x8 bhz = ldfrag(&Whhb[(size_t)(128 + br) * 128 + ko]);
            bf16x8 bhg = ldfrag(&Whhb[(size_t)(256 + br) * 128 + ko]);
            #pragma unroll
            for (int ta = 0; ta < 4; ++ta) {
                bf16x8 am = ldfrag(&hb [ta * 16 + rowA][ko]);
                bf16x8 ah = ldfrag(&sxb[ta * 16 + rowA][ko]);
                g[0][ta] = MFMA(am, bir, g[0][ta]);
                g[1][ta] = MFMA(am, biz, g[1][ta]);
                g[2][ta] = MFMA(am, big, g[2][ta]);
                g[3][ta] = MFMA(ah, bhr, g[3][ta]);
                g[4][ta] = MFMA(ah, bhz, g[4][ta]);
                g[5][ta] = MFMA(ah, bhg, g[5][ta]);
            }
        }
        const int d = n0 + col;
        float bir = bih[d], biz = bih[128 + d], big = bih[256 + d];
        float bhr = bhh[d], bhz = bhh[128 + d], bhg = bhh[256 + d];
        #pragma unroll
        for (int ta = 0; ta < 4; ++ta)
            #pragma unroll
            for (int rgi = 0; rgi < 4; ++rgi) {
                int rr = ta * 16 + rgrp * 4 + rgi;
                float rv = fsigmoid((g[0][ta][rgi] + bir) + (g[3][ta][rgi] + bhr));
                float zv = fsigmoid((g[1][ta][rgi] + biz) + (g[4][ta][rgi] + bhz));
                float gv = ftanh((g[2][ta][rgi] + big) + rv * (g[5][ta][rgi] + bhg));
                float selfv = bf2f(sxb[rr][d]);
                new_mem[(size_t)(base + rr) * DIM + d] = (1.f - zv) * gv + zv * selfv;
            }
    }
}

// ---------------------------------------------------------------------------
// K3 fused: 32 rows/block, 8 waves (512 thr). Q/u proj (MFMA) -> per-wave
// gather+scores+softmax+kvbar (wave-private, reg-prefetch) -> Wv/Wo/Wm1/Wm2
// MFMA back-end + LayerNorm.
// ---------------------------------------------------------------------------
__global__ __launch_bounds__(512) void k3_fused(
    const int* __restrict__ src,
    const float* __restrict__ memory, const float* __restrict__ new_mem,
    const int* __restrict__ winner,
    const int* __restrict__ sel_id, const float* __restrict__ sel_td,
    const int* __restrict__ sel_mk,
    const float* __restrict__ w_ta, const float* __restrict__ b_ta,
    const unsigned short* __restrict__ Wp,
    const float* __restrict__ bq, const float* __restrict__ bk,
    const float* __restrict__ bv, const float* __restrict__ bo,
    const float* __restrict__ bm1, const float* __restrict__ bm2,
    const float* __restrict__ ln_g, const float* __restrict__ ln_b,
    float* __restrict__ out)
{
    __shared__ unsigned short s_nfB[32][136];     // node features bf16
    __shared__ unsigned short s_qB [32][136];     // Q bf16
    __shared__ unsigned short s_u  [32][2][200];  // u = Wk_h^T Q_h, bf16
    __shared__ unsigned short s_kvb[32][2][200];  // kvbar bf16
    __shared__ unsigned long long s_pool64[6400]; // 51200B: kv staging / phase-B bufs
    __shared__ const float* s_nptr[32][16];
    __shared__ float s_td [32][16];
    __shared__ int   s_mk [32][16];
    __shared__ float s_qb [32][2];
    __shared__ float s_satt[32][2];
    __shared__ float s_at [8][2][16];
    __shared__ const float* s_ptr[32];

    const unsigned short* Wqb  = Wp + OFF_WQ;
    const unsigned short* WkTb = Wp + OFF_WKT;
    const unsigned short* Wvb  = Wp + OFF_WV;
    const unsigned short* Wob  = Wp + OFF_WO;
    const unsigned short* Wm1b = Wp + OFF_WM1;
    const unsigned short* Wm2b = Wp + OFF_WM2;

    const int tid  = threadIdx.x;
    const int base = blockIdx.x * 32;

    // ---- stage pointers + per-row neighbor metadata -------------------------
    if (tid < 32) {
        int v = src[base + tid];
        int wv = winner[v];
        s_ptr[tid] = (wv >= 0) ? (new_mem + (size_t)wv * DIM)
                               : (memory  + (size_t)v  * DIM);
    }
    {
        int r = tid >> 4, n = tid & 15;        // 512 threads = 32 rows x 16
        int id = sel_id[(base + r) * KSEL + n];
        int wi = winner[id];
        s_nptr[r][n] = (wi >= 0) ? (new_mem + (size_t)wi * DIM)
                                 : (memory  + (size_t)id * DIM);
        s_td[r][n] = sel_td[(base + r) * KSEL + n];
        s_mk[r][n] = sel_mk[(base + r) * KSEL + n];
    }
    __syncthreads();

    // ---- gather node features -> s_nfB --------------------------------------
    for (int idx = tid; idx < 32 * 32; idx += 512) {
        int r = idx >> 5, c4 = (idx & 31) << 2;
        float4 v = *(const float4*)&s_ptr[r][c4];
        *(uint2*)&s_nfB[r][c4] = pack4bf(v);
    }
    __syncthreads();

    const int w    = tid >> 6;        // 0..7
    const int l    = tid & 63;
    const int rowA = l & 15;
    const int kg   = l >> 4;
    const int col  = l & 15;
    const int rgrp = l >> 4;

    // ---- phase 0a: Q = nf @ Wq^T + bq (wave w: cols w*16..w*16+16) ----------
    {
        const int n0 = w * 16;
        f32x4 q0 = {0.f,0.f,0.f,0.f}, q1 = {0.f,0.f,0.f,0.f};
        #pragma unroll
        for (int kt = 0; kt < 4; ++kt) {
            int ko = kt * 32 + kg * 8;
            bf16x8 bfr = ldfrag(&Wqb[(size_t)(n0 + rowA) * 128 + ko]);
            q0 = MFMA(ldfrag(&s_nfB[     rowA][ko]), bfr, q0);
            q1 = MFMA(ldfrag(&s_nfB[16 + rowA][ko]), bfr, q1);
        }
        float bb = bq[n0 + col];
        #pragma unroll
        for (int rgi = 0; rgi < 4; ++rgi) {
            int rb = rgrp * 4 + rgi;
            s_qB[rb     ][n0 + col] = f2bf(q0[rgi] + bb);
            s_qB[rb + 16][n0 + col] = f2bf(q1[rgi] + bb);
        }
    }
    __syncthreads();

    // ---- phase 0b: qb[r][h] = Q_h . bk_h  (256 threads) ---------------------
    if (tid < 256) {
        int r = tid >> 3, rem = tid & 7, h = rem >> 2, p = rem & 3;
        float part = 0.f;
        #pragma unroll
        for (int j = 0; j < 16; ++j) {
            int dd = h * 64 + p * 16 + j;
            part += bf2f(s_qB[r][dd]) * bk[dd];
        }
        part += __shfl_xor(part, 1);
        part += __shfl_xor(part, 2);
        if (p == 0) s_qb[r][h] = part;
    }

    // ---- phase 0c: u = Wk_h^T Q_h (wave w: head w>>2, cols (w&3)*48) --------
    {
        const int h  = w >> 2;
        const int cb = (w & 3) * 48;
        f32x4 u[3][2];
        #pragma unroll
        for (int ct = 0; ct < 3; ++ct)
            #pragma unroll
            for (int ta = 0; ta < 2; ++ta) u[ct][ta] = (f32x4){0.f,0.f,0.f,0.f};
        #pragma unroll
        for (int kt = 0; kt < 2; ++kt) {
            int ko = kt * 32 + kg * 8;
            bf16x8 bfr[3];
            #pragma unroll
            for (int ct = 0; ct < 3; ++ct)
                bfr[ct] = ldfrag(&WkTb[(size_t)h * 12288 + (size_t)(cb + ct * 16 + rowA) * 64 + ko]);
            #pragma unroll
            for (int ta = 0; ta < 2; ++ta) {
                bf16x8 av = ldfrag(&s_qB[ta * 16 + rowA][h * 64 + ko]);
                #pragma unroll
                for (int ct = 0; ct < 3; ++ct)
                    u[ct][ta] = MFMA(av, bfr[ct], u[ct][ta]);
            }
        }
        #pragma unroll
        for (int ct = 0; ct < 3; ++ct)
            #pragma unroll
            for (int ta = 0; ta < 2; ++ta)
                #pragma unroll
                for (int rgi = 0; rgi < 4; ++rgi) {
                    int rr = ta * 16 + rgrp * 4 + rgi;
                    s_u[rr][h][cb + ct * 16 + col] = f2bf(u[ct][ta][rgi]);
                }
    }
    __syncthreads();

    // ---- phase A: per-wave 4 rows, wave-private, reg-prefetched gather ------
    {
        unsigned short (*kvbuf)[16][200] = (unsigned short (*)[16][200])s_pool64;
        float wt = w_ta[l], bt = b_ta[l];
        const int pfn = l >> 5;            // this lane's neighbor parity
        const int pfc = (l & 31) << 2;     // this lane's 4-col base

        float4 pf[8];
        {
            const int r = w * 4;
            #pragma unroll
            for (int it = 0; it < 8; ++it)
                pf[it] = *(const float4*)&s_nptr[r][it * 2 + pfn][pfc];
        }

        for (int rr = 0; rr < 4; ++rr) {
            const int r = w * 4 + rr;
            // write prefetched kv rows to LDS (bf16, packed)
            #pragma unroll
            for (int it = 0; it < 8; ++it)
                *(uint2*)&kvbuf[w][it * 2 + pfn][pfc] = pack4bf(pf[it]);
            // time encoding
            #pragma unroll
            for (int n = 0; n < 16; ++n) {
                float f = s_td[r][n] * wt + bt;
                kvbuf[w][n][128 + l] = f2bf((l & 1) ? __cosf(f) : __sinf(f));
            }
            // issue next row's gather now; latency hides under scores/kvbar
            if (rr < 3) {
                const int rn = r + 1;
                #pragma unroll
                for (int it = 0; it < 8; ++it)
                    pf[it] = *(const float4*)&s_nptr[rn][it * 2 + pfn][pfc];
            }
            __builtin_amdgcn_wave_barrier();

            // scores + masked softmax (wave-internal)
            {
                int h = (l >> 4) & 1, n = l & 15, half = l >> 5;
                float acc = (half == 0) ? s_qb[r][h] : 0.f;
                const unsigned short* kvrow = &kvbuf[w][n][half * 96];
                const unsigned short* urow  = &s_u[r][h][half * 96];
                #pragma unroll
                for (int k = 0; k < 96; k += 8) {
                    s16x8 kv8 = *(const s16x8*)&kvrow[k];
                    s16x8 u8  = *(const s16x8*)&urow[k];
                    #pragma unroll
                    for (int j = 0; j < 8; ++j)
                        acc += bf2f((unsigned short)kv8[j]) * bf2f((unsigned short)u8[j]);
                }
                acc += __shfl_xor(acc, 32);
                int mk = s_mk[r][n];
                float s = mk ? acc * 0.125f : -INFINITY;
                float mx = s;
                #pragma unroll
                for (int m = 1; m < 16; m <<= 1) mx = fmaxf(mx, __shfl_xor(mx, m));
                float p = (mk && mx > -1e37f) ? __expf(s - mx) : 0.f;
                float den = p;
                #pragma unroll
                for (int m = 1; m < 16; m <<= 1) den += __shfl_xor(den, m);
                float a = (den > 0.f) ? (p * rcpf_(den)) : 0.f;
                if (l < 32) s_at[w][h][n] = a;
                if (l == 0 || l == 16) s_satt[r][h] = (den > 0.f) ? 1.f : 0.f;
            }
            __builtin_amdgcn_wave_barrier();

            // kvbar[h][c] = sum_n at[h][n] * kv[n][c]  -> s_kvb (bf16)
            #pragma unroll
            for (int i = 0; i < 3; ++i) {
                int c = i * 64 + l;
                float k0 = 0.f, k1 = 0.f;
                #pragma unroll
                for (int n = 0; n < 16; ++n) {
                    float v = bf2f(kvbuf[w][n][c]);
                    k0 += s_at[w][0][n] * v;
                    k1 += s_at[w][1][n] * v;
                }
                s_kvb[r][0][c] = f2bf(k0);
                s_kvb[r][1][c] = f2bf(k1);
            }
            __builtin_amdgcn_wave_barrier();
        }
    }
    __syncthreads();

    // ---- phase B: MFMA back-end (pool aliased: kv staging is dead) ----------
    unsigned short (*s_aoB)[136] = (unsigned short (*)[136])s_pool64;
    unsigned short (*s_oB )[136] = (unsigned short (*)[136])((char*)s_pool64 + 8704);
    unsigned short (*s_h1B)[136] = (unsigned short (*)[136])((char*)s_pool64 + 17408);
    float          (*s_h2 )[128] = (float          (*)[128])((char*)s_pool64 + 26112);

    // out = Wv_h @ kvbar_h + satt_h*bv : wave w -> head w>>2, cols (w&3)*16
    {
        const int h  = w >> 2;
        const int c0 = (w & 3) * 16;
        f32x4 o0 = {0.f,0.f,0.f,0.f}, o1 = {0.f,0.f,0.f,0.f};
        #pragma unroll
        for (int kt = 0; kt < 6; ++kt) {
            int ko = kt * 32 + kg * 8;
            bf16x8 bfr = ldfrag(&Wvb[(size_t)(h * 64 + c0 + rowA) * 192 + ko]);
            o0 = MFMA(ldfrag(&s_kvb[     rowA][h][ko]), bfr, o0);
            o1 = MFMA(ldfrag(&s_kvb[16 + rowA][h][ko]), bfr, o1);
        }
        int d0 = h * 64 + c0 + col;
        float bv0 = bv[d0];
        #pragma unroll
        for (int rgi = 0; rgi < 4; ++rgi) {
            int rb = rgrp * 4 + rgi;
            s_oB[rb     ][d0] = f2bf(o0[rgi] + s_satt[rb     ][h] * bv0);
            s_oB[rb + 16][d0] = f2bf(o1[rgi] + s_satt[rb + 16][h] * bv0);
        }
    }
    __syncthreads();

    // ao = Wo @ out + bo
    {
        const int n0 = w * 16;
        f32x4 a0 = {0.f,0.f,0.f,0.f}, a1 = {0.f,0.f,0.f,0.f};
        #pragma unroll
        for (int kt = 0; kt < 4; ++kt) {
            int ko = kt * 32 + kg * 8;
            bf16x8 bfr = ldfrag(&Wob[(size_t)(n0 + rowA) * 128 + ko]);
            a0 = MFMA(ldfrag(&s_oB[     rowA][ko]), bfr, a0);
            a1 = MFMA(ldfrag(&s_oB[16 + rowA][ko]), bfr, a1);
        }
        float bb = bo[n0 + col];
        #pragma unroll
        for (int rgi = 0; rgi < 4; ++rgi) {
            int rb = rgrp * 4 + rgi;
            s_aoB[rb     ][n0 + col] = f2bf(a0[rgi] + bb);
            s_aoB[rb + 16][n0 + col] = f2bf(a1[rgi] + bb);
        }
    }
    __syncthreads();

    // h1 = relu(Wm1 @ [ao|nf] + bm1), K=256 (kt 0..3: ao, kt 4..7: nf)
    {
        const int n0 = w * 16;
        f32x4 a0 = {0.f,0.f,0.f,0.f}, a1 = {0.f,0.f,0.f,0.f};
        #pragma unroll
        for (int kt = 0; kt < 8; ++kt) {
            int ko = kt * 32 + kg * 8;
            bf16x8 av0 = (kt < 4) ? ldfrag(&s_aoB[     rowA][ko])
                                  : ldfrag(&s_nfB[     rowA][ko - 128]);
            bf16x8 av1 = (kt < 4) ? ldfrag(&s_aoB[16 + rowA][ko])
                                  : ldfrag(&s_nfB[16 + rowA][ko - 128]);
            bf16x8 bfr = ldfrag(&Wm1b[(size_t)(n0 + rowA) * 256 + ko]);
            a0 = MFMA(av0, bfr, a0);
            a1 = MFMA(av1, bfr, a1);
        }
        float bb = bm1[n0 + col];
        #pragma unroll
        for (int rgi = 0; rgi < 4; ++rgi) {
            int rb = rgrp * 4 + rgi;
            s_h1B[rb     ][n0 + col] = f2bf(fmaxf(a0[rgi] + bb, 0.f));
            s_h1B[rb + 16][n0 + col] = f2bf(fmaxf(a1[rgi] + bb, 0.f));
        }
    }
    __syncthreads();

    // h2 = Wm2 @ h1 + bm2 -> f32
    {
        const int n0 = w * 16;
        f32x4 a0 = {0.f,0.f,0.f,0.f}, a1 = {0.f,0.f,0.f,0.f};
        #pragma unroll
        for (int kt = 0; kt < 4; ++kt) {
            int ko = kt * 32 + kg * 8;
            bf16x8 bfr = ldfrag(&Wm2b[(size_t)(n0 + rowA) * 128 + ko]);
            a0 = MFMA(ldfrag(&s_h1B[     rowA][ko]), bfr, a0);
            a1 = MFMA(ldfrag(&s_h1B[16 + rowA][ko]), bfr, a1);
        }
        float bb = bm2[n0 + col];
        #pragma unroll
        for (int rgi = 0; rgi < 4; ++rgi) {
            int rb = rgrp * 4 + rgi;
            s_h2[rb     ][n0 + col] = a0[rgi] + bb;
            s_h2[rb + 16][n0 + col] = a1[rgi] + bb;
        }
    }
    __syncthreads();

    // LayerNorm: wave w -> rows w*4 .. w*4+3
    {
        float lg0 = ln_g[l], lg1 = ln_g[64 + l];
        float lb0 = ln_b[l], lb1 = ln_b[64 + l];
        #pragma unroll
        for (int i = 0; i < 4; ++i) {
            int r = w * 4 + i;
            float v0 = s_h2[r][l], v1 = s_h2[r][64 + l];
            float sum = v0 + v1;
            #pragma unroll
            for (int m = 1; m < 64; m <<= 1) sum += __shfl_xor(sum, m);
            float mean = sum * (1.f / 128.f);
            float e0 = v0 - mean, e1 = v1 - mean;
            float sq = e0 * e0 + e1 * e1;
            #pragma unroll
            for (int m = 1; m < 64; m <<= 1) sq += __shfl_xor(sq, m);
            float inv = rsqrtf(sq * (1.f / 128.f) + 1e-5f);
            out[(size_t)(base + r) * DIM + l]      = e0 * inv * lg0 + lb0;
            out[(size_t)(base + r) * DIM + 64 + l] = e1 * inv * lg1 + lb1;
        }
    }
}

// ---------------------------------------------------------------------------
extern "C" void kernel_launch(void* const* d_in, const int* in_sizes, int n_in,
                              void* d_out, int out_size, void* d_ws, size_t ws_size,
                              hipStream_t stream) {
    const int*   src         = (const int*)  d_in[0];
    const int*   dst         = (const int*)  d_in[1];
    const float* ts          = (const float*)d_in[2];
    const int*   nbr_ids     = (const int*)  d_in[3];
    const float* nbr_ts      = (const float*)d_in[4];
    const float* memory      = (const float*)d_in[5];
    const float* last_update = (const float*)d_in[6];
    const float* w_t_msg     = (const float*)d_in[7];
    const float* b_t_msg     = (const float*)d_in[8];
    const float* W_msg1      = (const float*)d_in[9];
    const float* b_msg1      = (const float*)d_in[10];
    const float* W_msg2      = (const float*)d_in[11];
    const float* b_msg2      = (const float*)d_in[12];
    const float* W_ih        = (const float*)d_in[13];
    const float* b_ih        = (const float*)d_in[14];
    const float* W_hh        = (const float*)d_in[15];
    const float* b_hh        = (const float*)d_in[16];
    const float* w_t_att     = (const float*)d_in[17];
    const float* b_t_att     = (const float*)d_in[18];
    const float* Wq          = (const float*)d_in[19];
    const float* bq          = (const float*)d_in[20];
    const float* Wk          = (const float*)d_in[21];
    const float* bk          = (const float*)d_in[22];
    const float* Wv          = (const float*)d_in[23];
    const float* bv          = (const float*)d_in[24];
    const float* Wo          = (const float*)d_in[25];
    const float* bo          = (const float*)d_in[26];
    const float* Wm1         = (const float*)d_in[27];
    const float* bm1         = (const float*)d_in[28];
    const float* Wm2         = (const float*)d_in[29];
    const float* bm2         = (const float*)d_in[30];
    const float* ln_g        = (const float*)d_in[31];
    const float* ln_b        = (const float*)d_in[32];
    float* out = (float*)d_out;

    char* ws = (char*)d_ws;
    size_t off = 0;
    float* new_mem = (float*)(ws + off); off += (size_t)2 * BATCH * DIM * 4;   // 8 MiB
    int*   winner  = (int*)  (ws + off); off += 2097152;                       // 2 MiB
    int*   sel_id  = (int*)  (ws + off); off += (size_t)BATCH * KSEL * 4;
    float* sel_td  = (float*)(ws + off); off += (size_t)BATCH * KSEL * 4;
    int*   sel_mk  = (int*)  (ws + off); off += (size_t)BATCH * KSEL * 4;
    unsigned short* Wpool = (unsigned short*)(ws + off); off += (size_t)CVT_TOT * 2;

    k_prep<<<NB_CVT, 256, 0, stream>>>(
        W_msg1, W_msg2, W_ih, W_hh, Wq, Wv, Wo, Wm1, Wm2, Wk, Wpool, winner);
    k1_mfma<<<(2 * BATCH) / 64, 512, 0, stream>>>(
        src, dst, ts, memory, last_update,
        w_t_msg, b_t_msg, Wpool, b_msg1, b_msg2, b_ih, b_hh, new_mem,
        winner, nbr_ids, nbr_ts, sel_id, sel_td, sel_mk);
    k3_fused<<<BATCH / 32, 512, 0, stream>>>(
        src, memory, new_mem, winner, sel_id, sel_td, sel_mk,
        w_t_att, b_t_att, Wpool, bq, bk, bv, bo, bm1, bm2, ln_g, ln_b, out);
}

// Round 12
// 62.491 us; speedup vs baseline: 4.1556x; 1.1563x over previous
//
#include <hip/hip_runtime.h>
#include <math.h>

#define BATCH  8192
#define NNODES 500000
#define DIM    128
#define TDIM   64
#define KNB    32
#define KSEL   16

// bf16 weight pool element offsets
#define OFF_W1   0
#define OFF_W2   40960
#define OFF_WIH  57344
#define OFF_WHH  106496
#define OFF_WQ   155648
#define OFF_WV   172032
#define OFF_WO   196608
#define OFF_WM1  212992
#define OFF_WM2  245760
#define OFF_WKT  262144
#define CVT_TOT  286720

#define NB_CVT  1120                  // CVT_TOT / 256 exactly

typedef float  f32x4  __attribute__((ext_vector_type(4)));
typedef __bf16 bf16x8 __attribute__((ext_vector_type(8)));
typedef short  s16x8  __attribute__((ext_vector_type(8)));

#define MFMA(a,b,c) __builtin_amdgcn_mfma_f32_16x16x32_bf16(a,b,c,0,0,0)

__device__ __forceinline__ float rcpf_(float x) { return __builtin_amdgcn_rcpf(x); }
__device__ __forceinline__ float fsigmoid(float x) { return rcpf_(1.f + __expf(-x)); }
__device__ __forceinline__ float ftanh(float x) {
    float e = __expf(2.f * x);
    return 1.f - 2.f * rcpf_(e + 1.f);
}
__device__ __forceinline__ unsigned short f2bf(float x) {
    unsigned u = __builtin_bit_cast(unsigned, x);
    unsigned r = (u + 0x7FFFu + ((u >> 16) & 1u)) >> 16;
    return (unsigned short)r;
}
__device__ __forceinline__ float bf2f(unsigned short u) {
    unsigned v = ((unsigned)u) << 16;
    return __builtin_bit_cast(float, v);
}
__device__ __forceinline__ bf16x8 ldfrag(const unsigned short* p) {
    s16x8 v = *(const s16x8*)p;
    return __builtin_bit_cast(bf16x8, v);
}
__device__ __forceinline__ uint2 pack4bf(float4 v) {
    uint2 pk;
    pk.x = (unsigned)f2bf(v.x) | ((unsigned)f2bf(v.y) << 16);
    pk.y = (unsigned)f2bf(v.z) | ((unsigned)f2bf(v.w) << 16);
    return pk;
}

// ---------------------------------------------------------------------------
// K_prep: weight->bf16 pool conversion + winner-array clear (grid-stride).
// ---------------------------------------------------------------------------
__global__ __launch_bounds__(256) void k_prep(
    const float* __restrict__ sW1, const float* __restrict__ sW2,
    const float* __restrict__ sWih, const float* __restrict__ sWhh,
    const float* __restrict__ sWq, const float* __restrict__ sWv,
    const float* __restrict__ sWo, const float* __restrict__ sWm1,
    const float* __restrict__ sWm2, const float* __restrict__ sWk,
    unsigned short* __restrict__ pool,
    int* __restrict__ winner)
{
    const int i = blockIdx.x * 256 + threadIdx.x;     // < CVT_TOT
    {
        float v;
        if      (i < OFF_W2)  { v = sW1 [i - OFF_W1 ]; }
        else if (i < OFF_WIH) { v = sW2 [i - OFF_W2 ]; }
        else if (i < OFF_WHH) { v = sWih[i - OFF_WIH]; }
        else if (i < OFF_WQ)  { v = sWhh[i - OFF_WHH]; }
        else if (i < OFF_WV)  { v = sWq [i - OFF_WQ ]; }
        else if (i < OFF_WO)  { v = sWv [i - OFF_WV ]; }
        else if (i < OFF_WM1) { v = sWo [i - OFF_WO ]; }
        else if (i < OFF_WM2) { v = sWm1[i - OFF_WM1]; }
        else if (i < OFF_WKT) { v = sWm2[i - OFF_WM2]; }
        else {
            int j = i - OFF_WKT;           // h*12288 + c*64 + dh
            int h = j / 12288, rem = j % 12288;
            int c = rem >> 6, dh = rem & 63;
            v = sWk[(size_t)(h * 64 + dh) * 192 + c];
        }
        pool[i] = f2bf(v);
    }
    for (int j = i; j < NNODES; j += NB_CVT * 256) winner[j] = -1;
}

// ---------------------------------------------------------------------------
// K1 (MFMA): prelude {winner scatter + WAVE-PARALLEL top-k} then msg MLP+GRU.
// 64 rows/block, 8 waves (512 thr). Wave w owns output cols [w*16, w*16+16).
// Top-k: rank-selection, 2 rows per wave per pass, 2 passes. Lane j owns
// neighbor j; rank = #{keys greater} + #{equal keys with smaller index};
// rank<16 lanes write slot 'rank'. Same stable selection as serial scan.
// ---------------------------------------------------------------------------
__global__ __launch_bounds__(512) void k1_mfma(
    const int* __restrict__ src, const int* __restrict__ dst, const float* __restrict__ ts,
    const float* __restrict__ memory, const float* __restrict__ last_update,
    const float* __restrict__ w_t, const float* __restrict__ b_t,
    const unsigned short* __restrict__ Wp,
    const float* __restrict__ b1, const float* __restrict__ b2,
    const float* __restrict__ bih, const float* __restrict__ bhh,
    float* __restrict__ new_mem,
    int* __restrict__ winner,
    const int* __restrict__ nbr_ids, const float* __restrict__ nbr_ts,
    int* __restrict__ sel_id, float* __restrict__ sel_td, int* __restrict__ sel_mk)
{
    __shared__ unsigned short sxb[64][328];   // [self|oth|te] bf16, pad 8
    __shared__ unsigned short hb [64][136];   // h1 then msg
    __shared__ int   s_node[64];
    __shared__ int   s_oth [64];
    __shared__ float s_dt  [64];

    const unsigned short* W1b  = Wp + OFF_W1;
    const unsigned short* W2b  = Wp + OFF_W2;
    const unsigned short* Wihb = Wp + OFF_WIH;
    const unsigned short* Whhb = Wp + OFF_WHH;

    const int tid  = threadIdx.x;
    const int bid  = blockIdx.x;
    const int base = bid * 64;

    // ---- prelude: winner scatter + parallel top-k ---------------------------
    if (tid < 64) {
        int i = bid * 64 + tid;
        int v = (i < BATCH) ? src[i] : dst[i - BATCH];
        atomicMax(&winner[v], i);
    }
    {
        const int w = tid >> 6, l = tid & 63;
        const int j = l & 31;                 // neighbor index within row
        // rows: pass p -> rloc = w*4 + p*2 + (l>>5)
        int   bq0 = bid * 32 + w * 4 + (l >> 5);
        int   bq1 = bq0 + 2;
        int   s0 = src[bq0], s1 = src[bq1];
        float t0 = ts[bq0],  t1 = ts[bq1];
        int   id0 = nbr_ids[(size_t)s0 * KNB + j];
        float nt0 = nbr_ts [(size_t)s0 * KNB + j];
        int   id1 = nbr_ids[(size_t)s1 * KNB + j];
        float nt1 = nbr_ts [(size_t)s1 * KNB + j];
        // pass 0
        {
            bool valid = (id0 >= 0) && (nt0 < t0 + 1e-6f);
            float key = valid ? nt0 : -1e30f;
            int rank = 0;
            #pragma unroll
            for (int m = 0; m < 32; ++m) {
                float ok = __shfl(key, (l & 32) + m);
                rank += (ok > key) || (ok == key && m < j);
            }
            if (rank < KSEL) {
                int oid = id0 < 0 ? 0 : (id0 > NNODES - 1 ? NNODES - 1 : id0);
                sel_id[bq0 * KSEL + rank] = valid ? oid : 0;
                sel_td[bq0 * KSEL + rank] = valid ? (t0 - nt0) : 0.f;
                sel_mk[bq0 * KSEL + rank] = valid ? 1 : 0;
            }
        }
        // pass 1
        {
            bool valid = (id1 >= 0) && (nt1 < t1 + 1e-6f);
            float key = valid ? nt1 : -1e30f;
            int rank = 0;
            #pragma unroll
            for (int m = 0; m < 32; ++m) {
                float ok = __shfl(key, (l & 32) + m);
                rank += (ok > key) || (ok == key && m < j);
            }
            if (rank < KSEL) {
                int oid = id1 < 0 ? 0 : (id1 > NNODES - 1 ? NNODES - 1 : id1);
                sel_id[bq1 * KSEL + rank] = valid ? oid : 0;
                sel_td[bq1 * KSEL + rank] = valid ? (t1 - nt1) : 0.f;
                sel_mk[bq1 * KSEL + rank] = valid ? 1 : 0;
            }
        }
    }

    // ---- main k1 body -------------------------------------------------------
    if (tid < 64) {
        int gi = base + tid;
        int node, oth; float t;
        if (gi < BATCH) { node = src[gi];         oth = dst[gi];         t = ts[gi]; }
        else            { node = dst[gi - BATCH]; oth = src[gi - BATCH]; t = ts[gi - BATCH]; }
        s_node[tid] = node;
        s_oth[tid]  = oth;
        s_dt[tid]   = t - last_update[node];
    }
    __syncthreads();

    for (int idx = tid; idx < 64 * 32; idx += 512) {
        int r = idx >> 5, c4 = (idx & 31) << 2;
        float4 vs = *(const float4*)&memory[(size_t)s_node[r] * DIM + c4];
        float4 vo = *(const float4*)&memory[(size_t)s_oth[r]  * DIM + c4];
        *(uint2*)&sxb[r][c4]       = pack4bf(vs);
        *(uint2*)&sxb[r][128 + c4] = pack4bf(vo);
    }
    for (int idx = tid; idx < 64 * TDIM; idx += 512) {
        int r = idx >> 6, c = idx & 63;
        float f = s_dt[r] * w_t[c] + b_t[c];
        sxb[r][256 + c] = f2bf((c & 1) ? __cosf(f) : __sinf(f));
    }
    __syncthreads();

    const int w    = tid >> 6;        // 0..7
    const int l    = tid & 63;
    const int rowA = l & 15;
    const int kg   = l >> 4;
    const int n0   = w * 16;
    const int col  = l & 15;
    const int rgrp = l >> 4;

    // ---- stage 1: h1 = relu(x @ W1^T + b1), K=320 ---------------------------
    {
        f32x4 a0 = {0.f,0.f,0.f,0.f}, a1 = {0.f,0.f,0.f,0.f};
        f32x4 a2 = {0.f,0.f,0.f,0.f}, a3 = {0.f,0.f,0.f,0.f};
        #pragma unroll
        for (int kt = 0; kt < 10; ++kt) {
            int ko = kt * 32 + kg * 8;
            bf16x8 bfr = ldfrag(&W1b[(size_t)(n0 + rowA) * 320 + ko]);
            a0 = MFMA(ldfrag(&sxb[     rowA][ko]), bfr, a0);
            a1 = MFMA(ldfrag(&sxb[16 + rowA][ko]), bfr, a1);
            a2 = MFMA(ldfrag(&sxb[32 + rowA][ko]), bfr, a2);
            a3 = MFMA(ldfrag(&sxb[48 + rowA][ko]), bfr, a3);
        }
        float bb = b1[n0 + col];
        #pragma unroll
        for (int rgi = 0; rgi < 4; ++rgi) {
            int rb = rgrp * 4 + rgi;
            hb[rb     ][n0 + col] = f2bf(fmaxf(a0[rgi] + bb, 0.f));
            hb[rb + 16][n0 + col] = f2bf(fmaxf(a1[rgi] + bb, 0.f));
            hb[rb + 32][n0 + col] = f2bf(fmaxf(a2[rgi] + bb, 0.f));
            hb[rb + 48][n0 + col] = f2bf(fmaxf(a3[rgi] + bb, 0.f));
        }
    }
    __syncthreads();

    // ---- stage 2: msg = h1 @ W2^T + b2, K=128 -------------------------------
    {
        f32x4 m0 = {0.f,0.f,0.f,0.f}, m1 = {0.f,0.f,0.f,0.f};
        f32x4 m2 = {0.f,0.f,0.f,0.f}, m3 = {0.f,0.f,0.f,0.f};
        #pragma unroll
        for (int kt = 0; kt < 4; ++kt) {
            int ko = kt * 32 + kg * 8;
            bf16x8 bfr = ldfrag(&W2b[(size_t)(n0 + rowA) * 128 + ko]);
            m0 = MFMA(ldfrag(&hb[     rowA][ko]), bfr, m0);
            m1 = MFMA(ldfrag(&hb[16 + rowA][ko]), bfr, m1);
            m2 = MFMA(ldfrag(&hb[32 + rowA][ko]), bfr, m2);
            m3 = MFMA(ldfrag(&hb[48 + rowA][ko]), bfr, m3);
        }
        __syncthreads();   // all h1 reads done before overwrite
        float bb = b2[n0 + col];
        #pragma unroll
        for (int rgi = 0; rgi < 4; ++rgi) {
            int rb = rgrp * 4 + rgi;
            hb[rb     ][n0 + col] = f2bf(m0[rgi] + bb);
            hb[rb + 16][n0 + col] = f2bf(m1[rgi] + bb);
            hb[rb + 32][n0 + col] = f2bf(m2[rgi] + bb);
            hb[rb + 48][n0 + col] = f2bf(m3[rgi] + bb);
        }
    }
    __syncthreads();

    // ---- stage 3: GRU gates, one 16-col pass per wave, 4 A-tiles ------------
    {
        f32x4 g[6][4];
        #pragma unroll
        for (int gi_ = 0; gi_ < 6; ++gi_)
            #pragma unroll
            for (int ta = 0; ta < 4; ++ta) g[gi_][ta] = (f32x4){0.f,0.f,0.f,0.f};
        #pragma unroll
        for (int kt = 0; kt < 4; ++kt) {
            int ko = kt * 32 + kg * 8;
            int br = n0 + rowA;
            bf16x8 bir = ldfrag(&Wihb[(size_t)(      br) * 128 + ko]);
            bf16x8 biz = ldfrag(&Wihb[(size_t)(128 + br) * 128 + ko]);
            bf16x8 big = ldfrag(&Wihb[(size_t)(256 + br) * 128 + ko]);
            bf16x8 bhr = ldfrag(&Whhb[(size_t)(      br) * 128 + ko]);
            bf16x8 bhz = ldfrag(&Whhb[(size_t)(128 + br) * 128 + ko]);
            bf16x8 bhg = ldfrag(&Whhb[(size_t)(256 + br) * 128 + ko]);
            #pragma unroll
            for (int ta = 0; ta < 4; ++ta) {
                bf16x8 am = ldfrag(&hb [ta * 16 + rowA][ko]);
                bf16x8 ah = ldfrag(&sxb[ta * 16 + rowA][ko]);
                g[0][ta] = MFMA(am, bir, g[0][ta]);
                g[1][ta] = MFMA(am, biz, g[1][ta]);
                g[2][ta] = MFMA(am, big, g[2][ta]);
                g[3][ta] = MFMA(ah, bhr, g[3][ta]);
                g[4][ta] = MFMA(ah, bhz, g[4][ta]);
                g[5][ta] = MFMA(ah, bhg, g[5][ta]);
            }
        }
        const int d = n0 + col;
        float bir = bih[d], biz = bih[128 + d], big = bih[256 + d];
        float bhr = bhh[d], bhz = bhh[128 + d], bhg = bhh[256 + d];
        #pragma unroll
        for (int ta = 0; ta < 4; ++ta)
            #pragma unroll
            for (int rgi = 0; rgi < 4; ++rgi) {
                int rr = ta * 16 + rgrp * 4 + rgi;
                float rv = fsigmoid((g[0][ta][rgi] + bir) + (g[3][ta][rgi] + bhr));
                float zv = fsigmoid((g[1][ta][rgi] + biz) + (g[4][ta][rgi] + bhz));
                float gv = ftanh((g[2][ta][rgi] + big) + rv * (g[5][ta][rgi] + bhg));
                float selfv = bf2f(sxb[rr][d]);
                new_mem[(size_t)(base + rr) * DIM + d] = (1.f - zv) * gv + zv * selfv;
            }
    }
}

// ---------------------------------------------------------------------------
// K3 fused: 32 rows/block, 8 waves (512 thr). Q/u proj (MFMA) -> per-wave
// gather+scores+softmax+kvbar (wave-private, reg-prefetch) -> Wv/Wo/Wm1/Wm2
// MFMA back-end + LayerNorm. u kept f32 in LDS (152 KB total, 1 block/CU).
// ---------------------------------------------------------------------------
__global__ __launch_bounds__(512) void k3_fused(
    const int* __restrict__ src,
    const float* __restrict__ memory, const float* __restrict__ new_mem,
    const int* __restrict__ winner,
    const int* __restrict__ sel_id, const float* __restrict__ sel_td,
    const int* __restrict__ sel_mk,
    const float* __restrict__ w_ta, const float* __restrict__ b_ta,
    const unsigned short* __restrict__ Wp,
    const float* __restrict__ bq, const float* __restrict__ bk,
    const float* __restrict__ bv, const float* __restrict__ bo,
    const float* __restrict__ bm1, const float* __restrict__ bm2,
    const float* __restrict__ ln_g, const float* __restrict__ ln_b,
    float* __restrict__ out)
{
    __shared__ unsigned short s_nfB[32][136];     // node features bf16
    __shared__ unsigned short s_qB [32][136];     // Q bf16
    __shared__ float          s_u  [32][2][200];  // u = Wk_h^T Q_h, f32
    __shared__ unsigned short s_kvb[32][2][200];  // kvbar bf16
    __shared__ unsigned long long s_pool64[6400]; // 51200B: kv staging / phase-B bufs
    __shared__ const float* s_nptr[32][16];
    __shared__ float s_td [32][16];
    __shared__ int   s_mk [32][16];
    __shared__ float s_qb [32][2];
    __shared__ float s_satt[32][2];
    __shared__ float s_at [8][2][16];
    __shared__ const float* s_ptr[32];

    const unsigned short* Wqb  = Wp + OFF_WQ;
    const unsigned short* WkTb = Wp + OFF_WKT;
    const unsigned short* Wvb  = Wp + OFF_WV;
    const unsigned short* Wob  = Wp + OFF_WO;
    const unsigned short* Wm1b = Wp + OFF_WM1;
    const unsigned short* Wm2b = Wp + OFF_WM2;

    const int tid  = threadIdx.x;
    const int base = blockIdx.x * 32;

    // ---- stage pointers + per-row neighbor metadata -------------------------
    if (tid < 32) {
        int v = src[base + tid];
        int wv = winner[v];
        s_ptr[tid] = (wv >= 0) ? (new_mem + (size_t)wv * DIM)
                               : (memory  + (size_t)v  * DIM);
    }
    {
        int r = tid >> 4, n = tid & 15;        // 512 threads = 32 rows x 16
        int id = sel_id[(base + r) * KSEL + n];
        int wi = winner[id];
        s_nptr[r][n] = (wi >= 0) ? (new_mem + (size_t)wi * DIM)
                                 : (memory  + (size_t)id * DIM);
        s_td[r][n] = sel_td[(base + r) * KSEL + n];
        s_mk[r][n] = sel_mk[(base + r) * KSEL + n];
    }
    __syncthreads();

    // ---- gather node features -> s_nfB --------------------------------------
    for (int idx = tid; idx < 32 * 32; idx += 512) {
        int r = idx >> 5, c4 = (idx & 31) << 2;
        float4 v = *(const float4*)&s_ptr[r][c4];
        *(uint2*)&s_nfB[r][c4] = pack4bf(v);
    }
    __syncthreads();

    const int w    = tid >> 6;        // 0..7
    const int l    = tid & 63;
    const int rowA = l & 15;
    const int kg   = l >> 4;
    const int col  = l & 15;
    const int rgrp = l >> 4;

    // ---- phase 0a: Q = nf @ Wq^T + bq (wave w: cols w*16..w*16+16) ----------
    {
        const int n0 = w * 16;
        f32x4 q0 = {0.f,0.f,0.f,0.f}, q1 = {0.f,0.f,0.f,0.f};
        #pragma unroll
        for (int kt = 0; kt < 4; ++kt) {
            int ko = kt * 32 + kg * 8;
            bf16x8 bfr = ldfrag(&Wqb[(size_t)(n0 + rowA) * 128 + ko]);
            q0 = MFMA(ldfrag(&s_nfB[     rowA][ko]), bfr, q0);
            q1 = MFMA(ldfrag(&s_nfB[16 + rowA][ko]), bfr, q1);
        }
        float bb = bq[n0 + col];
        #pragma unroll
        for (int rgi = 0; rgi < 4; ++rgi) {
            int rb = rgrp * 4 + rgi;
            s_qB[rb     ][n0 + col] = f2bf(q0[rgi] + bb);
            s_qB[rb + 16][n0 + col] = f2bf(q1[rgi] + bb);
        }
    }
    __syncthreads();

    // ---- phase 0b: qb[r][h] = Q_h . bk_h  (256 threads) ---------------------
    if (tid < 256) {
        int r = tid >> 3, rem = tid & 7, h = rem >> 2, p = rem & 3;
        float part = 0.f;
        #pragma unroll
        for (int j = 0; j < 16; ++j) {
            int dd = h * 64 + p * 16 + j;
            part += bf2f(s_qB[r][dd]) * bk[dd];
        }
        part += __shfl_xor(part, 1);
        part += __shfl_xor(part, 2);
        if (p == 0) s_qb[r][h] = part;
    }

    // ---- phase 0c: u = Wk_h^T Q_h (wave w: head w>>2, cols (w&3)*48) --------
    {
        const int h  = w >> 2;
        const int cb = (w & 3) * 48;
        f32x4 u[3][2];
        #pragma unroll
        for (int ct = 0; ct < 3; ++ct)
            #pragma unroll
            for (int ta = 0; ta < 2; ++ta) u[ct][ta] = (f32x4){0.f,0.f,0.f,0.f};
        #pragma unroll
        for (int kt = 0; kt < 2; ++kt) {
            int ko = kt * 32 + kg * 8;
            bf16x8 bfr[3];
            #pragma unroll
            for (int ct = 0; ct < 3; ++ct)
                bfr[ct] = ldfrag(&WkTb[(size_t)h * 12288 + (size_t)(cb + ct * 16 + rowA) * 64 + ko]);
            #pragma unroll
            for (int ta = 0; ta < 2; ++ta) {
                bf16x8 av = ldfrag(&s_qB[ta * 16 + rowA][h * 64 + ko]);
                #pragma unroll
                for (int ct = 0; ct < 3; ++ct)
                    u[ct][ta] = MFMA(av, bfr[ct], u[ct][ta]);
            }
        }
        #pragma unroll
        for (int ct = 0; ct < 3; ++ct)
            #pragma unroll
            for (int ta = 0; ta < 2; ++ta)
                #pragma unroll
                for (int rgi = 0; rgi < 4; ++rgi) {
                    int rr = ta * 16 + rgrp * 4 + rgi;
                    s_u[rr][h][cb + ct * 16 + col] = u[ct][ta][rgi];
                }
    }
    __syncthreads();

    // ---- phase A: per-wave 4 rows, wave-private, reg-prefetched gather ------
    {
        unsigned short (*kvbuf)[16][200] = (unsigned short (*)[16][200])s_pool64;
        float wt = w_ta[l], bt = b_ta[l];
        const int pfn = l >> 5;            // this lane's neighbor parity
        const int pfc = (l & 31) << 2;     // this lane's 4-col base

        float4 pf[8];
        {
            const int r = w * 4;
            #pragma unroll
            for (int it = 0; it < 8; ++it)
                pf[it] = *(const float4*)&s_nptr[r][it * 2 + pfn][pfc];
        }

        for (int rr = 0; rr < 4; ++rr) {
            const int r = w * 4 + rr;
            // write prefetched kv rows to LDS (bf16, packed)
            #pragma unroll
            for (int it = 0; it < 8; ++it)
                *(uint2*)&kvbuf[w][it * 2 + pfn][pfc] = pack4bf(pf[it]);
            // time encoding
            #pragma unroll
            for (int n = 0; n < 16; ++n) {
                float f = s_td[r][n] * wt + bt;
                kvbuf[w][n][128 + l] = f2bf((l & 1) ? __cosf(f) : __sinf(f));
            }
            // issue next row's gather now; latency hides under scores/kvbar
            if (rr < 3) {
                const int rn = r + 1;
                #pragma unroll
                for (int it = 0; it < 8; ++it)
                    pf[it] = *(const float4*)&s_nptr[rn][it * 2 + pfn][pfc];
            }
            __builtin_amdgcn_wave_barrier();

            // scores + masked softmax (wave-internal)
            {
                int h = (l >> 4) & 1, n = l & 15, half = l >> 5;
                float acc = (half == 0) ? s_qb[r][h] : 0.f;
                const unsigned short* kvrow = &kvbuf[w][n][half * 96];
                const float* urow = &s_u[r][h][half * 96];
                #pragma unroll
                for (int k = 0; k < 96; k += 8) {
                    s16x8 kv8 = *(const s16x8*)&kvrow[k];
                    #pragma unroll
                    for (int j = 0; j < 8; ++j)
                        acc += bf2f((unsigned short)kv8[j]) * urow[k + j];
                }
                acc += __shfl_xor(acc, 32);
                int mk = s_mk[r][n];
                float s = mk ? acc * 0.125f : -INFINITY;
                float mx = s;
                #pragma unroll
                for (int m = 1; m < 16; m <<= 1) mx = fmaxf(mx, __shfl_xor(mx, m));
                float p = (mk && mx > -1e37f) ? __expf(s - mx) : 0.f;
                float den = p;
                #pragma unroll
                for (int m = 1; m < 16; m <<= 1) den += __shfl_xor(den, m);
                float a = (den > 0.f) ? (p * rcpf_(den)) : 0.f;
                if (l < 32) s_at[w][h][n] = a;
                if (l == 0 || l == 16) s_satt[r][h] = (den > 0.f) ? 1.f : 0.f;
            }
            __builtin_amdgcn_wave_barrier();

            // kvbar[h][c] = sum_n at[h][n] * kv[n][c]  -> s_kvb (bf16)
            #pragma unroll
            for (int i = 0; i < 3; ++i) {
                int c = i * 64 + l;
                float k0 = 0.f, k1 = 0.f;
                #pragma unroll
                for (int n = 0; n < 16; ++n) {
                    float v = bf2f(kvbuf[w][n][c]);
                    k0 += s_at[w][0][n] * v;
                    k1 += s_at[w][1][n] * v;
                }
                s_kvb[r][0][c] = f2bf(k0);
                s_kvb[r][1][c] = f2bf(k1);
            }
            __builtin_amdgcn_wave_barrier();
        }
    }
    __syncthreads();

    // ---- phase B: MFMA back-end (pool aliased: kv staging is dead) ----------
    unsigned short (*s_aoB)[136] = (unsigned short (*)[136])s_pool64;
    unsigned short (*s_oB )[136] = (unsigned short (*)[136])((char*)s_pool64 + 8704);
    unsigned short (*s_h1B)[136] = (unsigned short (*)[136])((char*)s_pool64 + 17408);
    float          (*s_h2 )[128] = (float          (*)[128])((char*)s_pool64 + 26112);

    // out = Wv_h @ kvbar_h + satt_h*bv : wave w -> head w>>2, cols (w&3)*16
    {
        const int h  = w >> 2;
        const int c0 = (w & 3) * 16;
        f32x4 o0 = {0.f,0.f,0.f,0.f}, o1 = {0.f,0.f,0.f,0.f};
        #pragma unroll
        for (int kt = 0; kt < 6; ++kt) {
            int ko = kt * 32 + kg * 8;
            bf16x8 bfr = ldfrag(&Wvb[(size_t)(h * 64 + c0 + rowA) * 192 + ko]);
            o0 = MFMA(ldfrag(&s_kvb[     rowA][h][ko]), bfr, o0);
            o1 = MFMA(ldfrag(&s_kvb[16 + rowA][h][ko]), bfr, o1);
        }
        int d0 = h * 64 + c0 + col;
        float bv0 = bv[d0];
        #pragma unroll
        for (int rgi = 0; rgi < 4; ++rgi) {
            int rb = rgrp * 4 + rgi;
            s_oB[rb     ][d0] = f2bf(o0[rgi] + s_satt[rb     ][h] * bv0);
            s_oB[rb + 16][d0] = f2bf(o1[rgi] + s_satt[rb + 16][h] * bv0);
        }
    }
    __syncthreads();

    // ao = Wo @ out + bo
    {
        const int n0 = w * 16;
        f32x4 a0 = {0.f,0.f,0.f,0.f}, a1 = {0.f,0.f,0.f,0.f};
        #pragma unroll
        for (int kt = 0; kt < 4; ++kt) {
            int ko = kt * 32 + kg * 8;
            bf16x8 bfr = ldfrag(&Wob[(size_t)(n0 + rowA) * 128 + ko]);
            a0 = MFMA(ldfrag(&s_oB[     rowA][ko]), bfr, a0);
            a1 = MFMA(ldfrag(&s_oB[16 + rowA][ko]), bfr, a1);
        }
        float bb = bo[n0 + col];
        #pragma unroll
        for (int rgi = 0; rgi < 4; ++rgi) {
            int rb = rgrp * 4 + rgi;
            s_aoB[rb     ][n0 + col] = f2bf(a0[rgi] + bb);
            s_aoB[rb + 16][n0 + col] = f2bf(a1[rgi] + bb);
        }
    }
    __syncthreads();

    // h1 = relu(Wm1 @ [ao|nf] + bm1), K=256 (kt 0..3: ao, kt 4..7: nf)
    {
        const int n0 = w * 16;
        f32x4 a0 = {0.f,0.f,0.f,0.f}, a1 = {0.f,0.f,0.f,0.f};
        #pragma unroll
        for (int kt = 0; kt < 8; ++kt) {
            int ko = kt * 32 + kg * 8;
            bf16x8 av0 = (kt < 4) ? ldfrag(&s_aoB[     rowA][ko])
                                  : ldfrag(&s_nfB[     rowA][ko - 128]);
            bf16x8 av1 = (kt < 4) ? ldfrag(&s_aoB[16 + rowA][ko])
                                  : ldfrag(&s_nfB[16 + rowA][ko - 128]);
            bf16x8 bfr = ldfrag(&Wm1b[(size_t)(n0 + rowA) * 256 + ko]);
            a0 = MFMA(av0, bfr, a0);
            a1 = MFMA(av1, bfr, a1);
        }
        float bb = bm1[n0 + col];
        #pragma unroll
        for (int rgi = 0; rgi < 4; ++rgi) {
            int rb = rgrp * 4 + rgi;
            s_h1B[rb     ][n0 + col] = f2bf(fmaxf(a0[rgi] + bb, 0.f));
            s_h1B[rb + 16][n0 + col] = f2bf(fmaxf(a1[rgi] + bb, 0.f));
        }
    }
    __syncthreads();

    // h2 = Wm2 @ h1 + bm2 -> f32
    {
        const int n0 = w * 16;
        f32x4 a0 = {0.f,0.f,0.f,0.f}, a1 = {0.f,0.f,0.f,0.f};
        #pragma unroll
        for (int kt = 0; kt < 4; ++kt) {
            int ko = kt * 32 + kg * 8;
            bf16x8 bfr = ldfrag(&Wm2b[(size_t)(n0 + rowA) * 128 + ko]);
            a0 = MFMA(ldfrag(&s_h1B[     rowA][ko]), bfr, a0);
            a1 = MFMA(ldfrag(&s_h1B[16 + rowA][ko]), bfr, a1);
        }
        float bb = bm2[n0 + col];
        #pragma unroll
        for (int rgi = 0; rgi < 4; ++rgi) {
            int rb = rgrp * 4 + rgi;
            s_h2[rb     ][n0 + col] = a0[rgi] + bb;
            s_h2[rb + 16][n0 + col] = a1[rgi] + bb;
        }
    }
    __syncthreads();

    // LayerNorm: wave w -> rows w*4 .. w*4+3
    {
        float lg0 = ln_g[l], lg1 = ln_g[64 + l];
        float lb0 = ln_b[l], lb1 = ln_b[64 + l];
        #pragma unroll
        for (int i = 0; i < 4; ++i) {
            int r = w * 4 + i;
            float v0 = s_h2[r][l], v1 = s_h2[r][64 + l];
            float sum = v0 + v1;
            #pragma unroll
            for (int m = 1; m < 64; m <<= 1) sum += __shfl_xor(sum, m);
            float mean = sum * (1.f / 128.f);
            float e0 = v0 - mean, e1 = v1 - mean;
            float sq = e0 * e0 + e1 * e1;
            #pragma unroll
            for (int m = 1; m < 64; m <<= 1) sq += __shfl_xor(sq, m);
            float inv = rsqrtf(sq * (1.f / 128.f) + 1e-5f);
            out[(size_t)(base + r) * DIM + l]      = e0 * inv * lg0 + lb0;
            out[(size_t)(base + r) * DIM + 64 + l] = e1 * inv * lg1 + lb1;
        }
    }
}

// ---------------------------------------------------------------------------
extern "C" void kernel_launch(void* const* d_in, const int* in_sizes, int n_in,
                              void* d_out, int out_size, void* d_ws, size_t ws_size,
                              hipStream_t stream) {
    const int*   src         = (const int*)  d_in[0];
    const int*   dst         = (const int*)  d_in[1];
    const float* ts          = (const float*)d_in[2];
    const int*   nbr_ids     = (const int*)  d_in[3];
    const float* nbr_ts      = (const float*)d_in[4];
    const float* memory      = (const float*)d_in[5];
    const float* last_update = (const float*)d_in[6];
    const float* w_t_msg     = (const float*)d_in[7];
    const float* b_t_msg     = (const float*)d_in[8];
    const float* W_msg1      = (const float*)d_in[9];
    const float* b_msg1      = (const float*)d_in[10];
    const float* W_msg2      = (const float*)d_in[11];
    const float* b_msg2      = (const float*)d_in[12];
    const float* W_ih        = (const float*)d_in[13];
    const float* b_ih        = (const float*)d_in[14];
    const float* W_hh        = (const float*)d_in[15];
    const float* b_hh        = (const float*)d_in[16];
    const float* w_t_att     = (const float*)d_in[17];
    const float* b_t_att     = (const float*)d_in[18];
    const float* Wq          = (const float*)d_in[19];
    const float* bq          = (const float*)d_in[20];
    const float* Wk          = (const float*)d_in[21];
    const float* bk          = (const float*)d_in[22];
    const float* Wv          = (const float*)d_in[23];
    const float* bv          = (const float*)d_in[24];
    const float* Wo          = (const float*)d_in[25];
    const float* bo          = (const float*)d_in[26];
    const float* Wm1         = (const float*)d_in[27];
    const float* bm1         = (const float*)d_in[28];
    const float* Wm2         = (const float*)d_in[29];
    const float* bm2         = (const float*)d_in[30];
    const float* ln_g        = (const float*)d_in[31];
    const float* ln_b        = (const float*)d_in[32];
    float* out = (float*)d_out;

    char* ws = (char*)d_ws;
    size_t off = 0;
    float* new_mem = (float*)(ws + off); off += (size_t)2 * BATCH * DIM * 4;   // 8 MiB
    int*   winner  = (int*)  (ws + off); off += 2097152;                       // 2 MiB
    int*   sel_id  = (int*)  (ws + off); off += (size_t)BATCH * KSEL * 4;
    float* sel_td  = (float*)(ws + off); off += (size_t)BATCH * KSEL * 4;
    int*   sel_mk  = (int*)  (ws + off); off += (size_t)BATCH * KSEL * 4;
    unsigned short* Wpool = (unsigned short*)(ws + off); off += (size_t)CVT_TOT * 2;

    k_prep<<<NB_CVT, 256, 0, stream>>>(
        W_msg1, W_msg2, W_ih, W_hh, Wq, Wv, Wo, Wm1, Wm2, Wk, Wpool, winner);
    k1_mfma<<<(2 * BATCH) / 64, 512, 0, stream>>>(
        src, dst, ts, memory, last_update,
        w_t_msg, b_t_msg, Wpool, b_msg1, b_msg2, b_ih, b_hh, new_mem,
        winner, nbr_ids, nbr_ts, sel_id, sel_td, sel_mk);
    k3_fused<<<BATCH / 32, 512, 0, stream>>>(
        src, memory, new_mem, winner, sel_id, sel_td, sel_mk,
        w_t_att, b_t_att, Wpool, bq, bk, bv, bo, bm1, bm2, ln_g, ln_b, out);
}

// Round 13
// 60.260 us; speedup vs baseline: 4.3095x; 1.0370x over previous
//
#include <hip/hip_runtime.h>
#include <math.h>

#define BATCH  8192
#define NNODES 500000
#define DIM    128
#define TDIM   64
#define KNB    32
#define KSEL   16

// bf16 weight pool element offsets
#define OFF_W1   0
#define OFF_W2   40960
#define OFF_WIH  57344
#define OFF_WHH  106496
#define OFF_WQ   155648
#define OFF_WV   172032
#define OFF_WO   196608
#define OFF_WM1  212992
#define OFF_WM2  245760
#define OFF_WKT  262144
#define CVT_TOT  286720

#define NB_CVT  1120                  // CVT_TOT / 256 exactly

typedef float  f32x4  __attribute__((ext_vector_type(4)));
typedef __bf16 bf16x8 __attribute__((ext_vector_type(8)));
typedef short  s16x8  __attribute__((ext_vector_type(8)));

#define MFMA(a,b,c) __builtin_amdgcn_mfma_f32_16x16x32_bf16(a,b,c,0,0,0)

__device__ __forceinline__ float rcpf_(float x) { return __builtin_amdgcn_rcpf(x); }
__device__ __forceinline__ float fsigmoid(float x) { return rcpf_(1.f + __expf(-x)); }
__device__ __forceinline__ float ftanh(float x) {
    float e = __expf(2.f * x);
    return 1.f - 2.f * rcpf_(e + 1.f);
}
__device__ __forceinline__ unsigned short f2bf(float x) {
    unsigned u = __builtin_bit_cast(unsigned, x);
    unsigned r = (u + 0x7FFFu + ((u >> 16) & 1u)) >> 16;
    return (unsigned short)r;
}
__device__ __forceinline__ float bf2f(unsigned short u) {
    unsigned v = ((unsigned)u) << 16;
    return __builtin_bit_cast(float, v);
}
__device__ __forceinline__ bf16x8 ldfrag(const unsigned short* p) {
    s16x8 v = *(const s16x8*)p;
    return __builtin_bit_cast(bf16x8, v);
}
__device__ __forceinline__ uint2 pack4bf(float4 v) {
    uint2 pk;
    pk.x = (unsigned)f2bf(v.x) | ((unsigned)f2bf(v.y) << 16);
    pk.y = (unsigned)f2bf(v.z) | ((unsigned)f2bf(v.w) << 16);
    return pk;
}

// ---------------------------------------------------------------------------
// K_prep: weight->bf16 pool conversion + winner-array clear (grid-stride).
// ---------------------------------------------------------------------------
__global__ __launch_bounds__(256) void k_prep(
    const float* __restrict__ sW1, const float* __restrict__ sW2,
    const float* __restrict__ sWih, const float* __restrict__ sWhh,
    const float* __restrict__ sWq, const float* __restrict__ sWv,
    const float* __restrict__ sWo, const float* __restrict__ sWm1,
    const float* __restrict__ sWm2, const float* __restrict__ sWk,
    unsigned short* __restrict__ pool,
    int* __restrict__ winner)
{
    const int i = blockIdx.x * 256 + threadIdx.x;     // < CVT_TOT
    {
        float v;
        if      (i < OFF_W2)  { v = sW1 [i - OFF_W1 ]; }
        else if (i < OFF_WIH) { v = sW2 [i - OFF_W2 ]; }
        else if (i < OFF_WHH) { v = sWih[i - OFF_WIH]; }
        else if (i < OFF_WQ)  { v = sWhh[i - OFF_WHH]; }
        else if (i < OFF_WV)  { v = sWq [i - OFF_WQ ]; }
        else if (i < OFF_WO)  { v = sWv [i - OFF_WV ]; }
        else if (i < OFF_WM1) { v = sWo [i - OFF_WO ]; }
        else if (i < OFF_WM2) { v = sWm1[i - OFF_WM1]; }
        else if (i < OFF_WKT) { v = sWm2[i - OFF_WM2]; }
        else {
            int j = i - OFF_WKT;           // h*12288 + c*64 + dh
            int h = j / 12288, rem = j % 12288;
            int c = rem >> 6, dh = rem & 63;
            v = sWk[(size_t)(h * 64 + dh) * 192 + c];
        }
        pool[i] = f2bf(v);
    }
    for (int j = i; j < NNODES; j += NB_CVT * 256) winner[j] = -1;
}

// ---------------------------------------------------------------------------
// K1 (MFMA): per-thread direct gather issued FIRST (latency hides under the
// wave-parallel top-k prelude), then msg MLP + GRU. 64 rows/block, 8 waves.
// ---------------------------------------------------------------------------
__global__ __launch_bounds__(512) void k1_mfma(
    const int* __restrict__ src, const int* __restrict__ dst, const float* __restrict__ ts,
    const float* __restrict__ memory, const float* __restrict__ last_update,
    const float* __restrict__ w_t, const float* __restrict__ b_t,
    const unsigned short* __restrict__ Wp,
    const float* __restrict__ b1, const float* __restrict__ b2,
    const float* __restrict__ bih, const float* __restrict__ bhh,
    float* __restrict__ new_mem,
    int* __restrict__ winner,
    const int* __restrict__ nbr_ids, const float* __restrict__ nbr_ts,
    int* __restrict__ sel_id, float* __restrict__ sel_td, int* __restrict__ sel_mk)
{
    __shared__ unsigned short sxb[64][328];   // [self|oth|te] bf16, pad 8
    __shared__ unsigned short hb [64][136];   // h1 then msg
    __shared__ float s_dt[64];

    const unsigned short* W1b  = Wp + OFF_W1;
    const unsigned short* W2b  = Wp + OFF_W2;
    const unsigned short* Wihb = Wp + OFF_WIH;
    const unsigned short* Whhb = Wp + OFF_WHH;

    const int tid  = threadIdx.x;
    const int bid  = blockIdx.x;
    const int base = bid * 64;

    // ---- A: issue main-gather loads (no LDS dependency; wave-uniform branch)
    float4 vs[4], vo[4];
    #pragma unroll
    for (int k = 0; k < 4; ++k) {
        int idx = tid + k * 512;
        int r = idx >> 5, c4 = (idx & 31) << 2;
        int gi = base + r;
        bool isrc = gi < BATCH;
        int node = isrc ? src[gi] : dst[gi - BATCH];
        int oth  = isrc ? dst[gi] : src[gi - BATCH];
        vs[k] = *(const float4*)&memory[(size_t)node * DIM + c4];
        vo[k] = *(const float4*)&memory[(size_t)oth  * DIM + c4];
    }

    // ---- B: prelude: winner scatter + wave-parallel top-k -------------------
    if (tid < 64) {
        int i = bid * 64 + tid;
        int v = (i < BATCH) ? src[i] : dst[i - BATCH];
        atomicMax(&winner[v], i);
    }
    {
        const int w = tid >> 6, l = tid & 63;
        const int j = l & 31;
        int   bq0 = bid * 32 + w * 4 + (l >> 5);
        int   bq1 = bq0 + 2;
        int   s0 = src[bq0], s1 = src[bq1];
        float t0 = ts[bq0],  t1 = ts[bq1];
        int   id0 = nbr_ids[(size_t)s0 * KNB + j];
        float nt0 = nbr_ts [(size_t)s0 * KNB + j];
        int   id1 = nbr_ids[(size_t)s1 * KNB + j];
        float nt1 = nbr_ts [(size_t)s1 * KNB + j];
        {
            bool valid = (id0 >= 0) && (nt0 < t0 + 1e-6f);
            float key = valid ? nt0 : -1e30f;
            int rank = 0;
            #pragma unroll
            for (int m = 0; m < 32; ++m) {
                float ok = __shfl(key, (l & 32) + m);
                rank += (ok > key) || (ok == key && m < j);
            }
            if (rank < KSEL) {
                int oid = id0 < 0 ? 0 : (id0 > NNODES - 1 ? NNODES - 1 : id0);
                sel_id[bq0 * KSEL + rank] = valid ? oid : 0;
                sel_td[bq0 * KSEL + rank] = valid ? (t0 - nt0) : 0.f;
                sel_mk[bq0 * KSEL + rank] = valid ? 1 : 0;
            }
        }
        {
            bool valid = (id1 >= 0) && (nt1 < t1 + 1e-6f);
            float key = valid ? nt1 : -1e30f;
            int rank = 0;
            #pragma unroll
            for (int m = 0; m < 32; ++m) {
                float ok = __shfl(key, (l & 32) + m);
                rank += (ok > key) || (ok == key && m < j);
            }
            if (rank < KSEL) {
                int oid = id1 < 0 ? 0 : (id1 > NNODES - 1 ? NNODES - 1 : id1);
                sel_id[bq1 * KSEL + rank] = valid ? oid : 0;
                sel_td[bq1 * KSEL + rank] = valid ? (t1 - nt1) : 0.f;
                sel_mk[bq1 * KSEL + rank] = valid ? 1 : 0;
            }
        }
    }

    // ---- C: per-row dt ------------------------------------------------------
    if (tid < 64) {
        int gi = base + tid;
        bool isrc = gi < BATCH;
        int node = isrc ? src[gi] : dst[gi - BATCH];
        float t  = isrc ? ts[gi]  : ts[gi - BATCH];
        s_dt[tid] = t - last_update[node];
    }

    // ---- D: pack + store gather (loads already in flight) -------------------
    #pragma unroll
    for (int k = 0; k < 4; ++k) {
        int idx = tid + k * 512;
        int r = idx >> 5, c4 = (idx & 31) << 2;
        *(uint2*)&sxb[r][c4]       = pack4bf(vs[k]);
        *(uint2*)&sxb[r][128 + c4] = pack4bf(vo[k]);
    }
    __syncthreads();

    // ---- E: time encoding ---------------------------------------------------
    for (int idx = tid; idx < 64 * TDIM; idx += 512) {
        int r = idx >> 6, c = idx & 63;
        float f = s_dt[r] * w_t[c] + b_t[c];
        sxb[r][256 + c] = f2bf((c & 1) ? __cosf(f) : __sinf(f));
    }
    __syncthreads();

    const int w    = tid >> 6;        // 0..7
    const int l    = tid & 63;
    const int rowA = l & 15;
    const int kg   = l >> 4;
    const int n0   = w * 16;
    const int col  = l & 15;
    const int rgrp = l >> 4;

    // ---- stage 1: h1 = relu(x @ W1^T + b1), K=320 ---------------------------
    {
        f32x4 a0 = {0.f,0.f,0.f,0.f}, a1 = {0.f,0.f,0.f,0.f};
        f32x4 a2 = {0.f,0.f,0.f,0.f}, a3 = {0.f,0.f,0.f,0.f};
        #pragma unroll
        for (int kt = 0; kt < 10; ++kt) {
            int ko = kt * 32 + kg * 8;
            bf16x8 bfr = ldfrag(&W1b[(size_t)(n0 + rowA) * 320 + ko]);
            a0 = MFMA(ldfrag(&sxb[     rowA][ko]), bfr, a0);
            a1 = MFMA(ldfrag(&sxb[16 + rowA][ko]), bfr, a1);
            a2 = MFMA(ldfrag(&sxb[32 + rowA][ko]), bfr, a2);
            a3 = MFMA(ldfrag(&sxb[48 + rowA][ko]), bfr, a3);
        }
        float bb = b1[n0 + col];
        #pragma unroll
        for (int rgi = 0; rgi < 4; ++rgi) {
            int rb = rgrp * 4 + rgi;
            hb[rb     ][n0 + col] = f2bf(fmaxf(a0[rgi] + bb, 0.f));
            hb[rb + 16][n0 + col] = f2bf(fmaxf(a1[rgi] + bb, 0.f));
            hb[rb + 32][n0 + col] = f2bf(fmaxf(a2[rgi] + bb, 0.f));
            hb[rb + 48][n0 + col] = f2bf(fmaxf(a3[rgi] + bb, 0.f));
        }
    }
    __syncthreads();

    // ---- stage 2: msg = h1 @ W2^T + b2, K=128 -------------------------------
    {
        f32x4 m0 = {0.f,0.f,0.f,0.f}, m1 = {0.f,0.f,0.f,0.f};
        f32x4 m2 = {0.f,0.f,0.f,0.f}, m3 = {0.f,0.f,0.f,0.f};
        #pragma unroll
        for (int kt = 0; kt < 4; ++kt) {
            int ko = kt * 32 + kg * 8;
            bf16x8 bfr = ldfrag(&W2b[(size_t)(n0 + rowA) * 128 + ko]);
            m0 = MFMA(ldfrag(&hb[     rowA][ko]), bfr, m0);
            m1 = MFMA(ldfrag(&hb[16 + rowA][ko]), bfr, m1);
            m2 = MFMA(ldfrag(&hb[32 + rowA][ko]), bfr, m2);
            m3 = MFMA(ldfrag(&hb[48 + rowA][ko]), bfr, m3);
        }
        __syncthreads();   // all h1 reads done before overwrite
        float bb = b2[n0 + col];
        #pragma unroll
        for (int rgi = 0; rgi < 4; ++rgi) {
            int rb = rgrp * 4 + rgi;
            hb[rb     ][n0 + col] = f2bf(m0[rgi] + bb);
            hb[rb + 16][n0 + col] = f2bf(m1[rgi] + bb);
            hb[rb + 32][n0 + col] = f2bf(m2[rgi] + bb);
            hb[rb + 48][n0 + col] = f2bf(m3[rgi] + bb);
        }
    }
    __syncthreads();

    // ---- stage 3: GRU gates, one 16-col pass per wave, 4 A-tiles ------------
    {
        f32x4 g[6][4];
        #pragma unroll
        for (int gi_ = 0; gi_ < 6; ++gi_)
            #pragma unroll
            for (int ta = 0; ta < 4; ++ta) g[gi_][ta] = (f32x4){0.f,0.f,0.f,0.f};
        #pragma unroll
        for (int kt = 0; kt < 4; ++kt) {
            int ko = kt * 32 + kg * 8;
            int br = n0 + rowA;
            bf16x8 bir = ldfrag(&Wihb[(size_t)(      br) * 128 + ko]);
            bf16x8 biz = ldfrag(&Wihb[(size_t)(128 + br) * 128 + ko]);
            bf16x8 big = ldfrag(&Wihb[(size_t)(256 + br) * 128 + ko]);
            bf16x8 bhr = ldfrag(&Whhb[(size_t)(      br) * 128 + ko]);
            bf16x8 bhz = ldfrag(&Whhb[(size_t)(128 + br) * 128 + ko]);
            bf16x8 bhg = ldfrag(&Whhb[(size_t)(256 + br) * 128 + ko]);
            #pragma unroll
            for (int ta = 0; ta < 4; ++ta) {
                bf16x8 am = ldfrag(&hb [ta * 16 + rowA][ko]);
                bf16x8 ah = ldfrag(&sxb[ta * 16 + rowA][ko]);
                g[0][ta] = MFMA(am, bir, g[0][ta]);
                g[1][ta] = MFMA(am, biz, g[1][ta]);
                g[2][ta] = MFMA(am, big, g[2][ta]);
                g[3][ta] = MFMA(ah, bhr, g[3][ta]);
                g[4][ta] = MFMA(ah, bhz, g[4][ta]);
                g[5][ta] = MFMA(ah, bhg, g[5][ta]);
            }
        }
        const int d = n0 + col;
        float bir = bih[d], biz = bih[128 + d], big = bih[256 + d];
        float bhr = bhh[d], bhz = bhh[128 + d], bhg = bhh[256 + d];
        #pragma unroll
        for (int ta = 0; ta < 4; ++ta)
            #pragma unroll
            for (int rgi = 0; rgi < 4; ++rgi) {
                int rr = ta * 16 + rgrp * 4 + rgi;
                float rv = fsigmoid((g[0][ta][rgi] + bir) + (g[3][ta][rgi] + bhr));
                float zv = fsigmoid((g[1][ta][rgi] + biz) + (g[4][ta][rgi] + bhz));
                float gv = ftanh((g[2][ta][rgi] + big) + rv * (g[5][ta][rgi] + bhg));
                float selfv = bf2f(sxb[rr][d]);
                new_mem[(size_t)(base + rr) * DIM + d] = (1.f - zv) * gv + zv * selfv;
            }
    }
}

// ---------------------------------------------------------------------------
// K3 fused: 32 rows/block, 8 waves. nf gather direct; kv row-0 prefetch
// issued before phase 0 (latency hides under Q/u MFMAs); kvbar u32-pair LDS
// reads; u f32 in LDS. Phase A wave-private with reg-prefetch.
// ---------------------------------------------------------------------------
__global__ __launch_bounds__(512) void k3_fused(
    const int* __restrict__ src,
    const float* __restrict__ memory, const float* __restrict__ new_mem,
    const int* __restrict__ winner,
    const int* __restrict__ sel_id, const float* __restrict__ sel_td,
    const int* __restrict__ sel_mk,
    const float* __restrict__ w_ta, const float* __restrict__ b_ta,
    const unsigned short* __restrict__ Wp,
    const float* __restrict__ bq, const float* __restrict__ bk,
    const float* __restrict__ bv, const float* __restrict__ bo,
    const float* __restrict__ bm1, const float* __restrict__ bm2,
    const float* __restrict__ ln_g, const float* __restrict__ ln_b,
    float* __restrict__ out)
{
    __shared__ unsigned short s_nfB[32][136];     // node features bf16
    __shared__ unsigned short s_qB [32][136];     // Q bf16
    __shared__ float          s_u  [32][2][200];  // u = Wk_h^T Q_h, f32
    __shared__ unsigned short s_kvb[32][2][200];  // kvbar bf16
    __shared__ unsigned long long s_pool64[6400]; // 51200B: kv staging / phase-B bufs
    __shared__ const float* s_nptr[32][16];
    __shared__ float s_td [32][16];
    __shared__ int   s_mk [32][16];
    __shared__ float s_qb [32][2];
    __shared__ float s_satt[32][2];
    __shared__ float s_at [8][2][16];

    const unsigned short* Wqb  = Wp + OFF_WQ;
    const unsigned short* WkTb = Wp + OFF_WKT;
    const unsigned short* Wvb  = Wp + OFF_WV;
    const unsigned short* Wob  = Wp + OFF_WO;
    const unsigned short* Wm1b = Wp + OFF_WM1;
    const unsigned short* Wm2b = Wp + OFF_WM2;

    const int tid  = threadIdx.x;
    const int base = blockIdx.x * 32;

    // ---- per-row neighbor metadata ------------------------------------------
    {
        int r = tid >> 4, n = tid & 15;        // 512 threads = 32 rows x 16
        int id = sel_id[(base + r) * KSEL + n];
        int wi = winner[id];
        s_nptr[r][n] = (wi >= 0) ? (new_mem + (size_t)wi * DIM)
                                 : (memory  + (size_t)id * DIM);
        s_td[r][n] = sel_td[(base + r) * KSEL + n];
        s_mk[r][n] = sel_mk[(base + r) * KSEL + n];
    }

    // ---- nf gather (direct, no LDS dependency) ------------------------------
    #pragma unroll
    for (int k = 0; k < 2; ++k) {
        int idx = tid + k * 512;
        int r = idx >> 5, c4 = (idx & 31) << 2;
        int v = src[base + r];
        int wv = winner[v];
        const float* p = (wv >= 0) ? (new_mem + (size_t)wv * DIM)
                                   : (memory  + (size_t)v  * DIM);
        float4 val = *(const float4*)&p[c4];
        *(uint2*)&s_nfB[r][c4] = pack4bf(val);
    }
    __syncthreads();

    const int w    = tid >> 6;        // 0..7
    const int l    = tid & 63;
    const int rowA = l & 15;
    const int kg   = l >> 4;
    const int col  = l & 15;
    const int rgrp = l >> 4;

    // ---- prefetch phase-A row 0 kv (latency hides under phase 0 MFMAs) -----
    const int pfn = l >> 5;
    const int pfc = (l & 31) << 2;
    float4 pf[8];
    {
        const int r = w * 4;
        #pragma unroll
        for (int it = 0; it < 8; ++it)
            pf[it] = *(const float4*)&s_nptr[r][it * 2 + pfn][pfc];
    }

    // ---- phase 0a: Q = nf @ Wq^T + bq (wave w: cols w*16..w*16+16) ----------
    {
        const int n0 = w * 16;
        f32x4 q0 = {0.f,0.f,0.f,0.f}, q1 = {0.f,0.f,0.f,0.f};
        #pragma unroll
        for (int kt = 0; kt < 4; ++kt) {
            int ko = kt * 32 + kg * 8;
            bf16x8 bfr = ldfrag(&Wqb[(size_t)(n0 + rowA) * 128 + ko]);
            q0 = MFMA(ldfrag(&s_nfB[     rowA][ko]), bfr, q0);
            q1 = MFMA(ldfrag(&s_nfB[16 + rowA][ko]), bfr, q1);
        }
        float bb = bq[n0 + col];
        #pragma unroll
        for (int rgi = 0; rgi < 4; ++rgi) {
            int rb = rgrp * 4 + rgi;
            s_qB[rb     ][n0 + col] = f2bf(q0[rgi] + bb);
            s_qB[rb + 16][n0 + col] = f2bf(q1[rgi] + bb);
        }
    }
    __syncthreads();

    // ---- phase 0b: qb[r][h] = Q_h . bk_h  (256 threads) ---------------------
    if (tid < 256) {
        int r = tid >> 3, rem = tid & 7, h = rem >> 2, p = rem & 3;
        float part = 0.f;
        #pragma unroll
        for (int j = 0; j < 16; ++j) {
            int dd = h * 64 + p * 16 + j;
            part += bf2f(s_qB[r][dd]) * bk[dd];
        }
        part += __shfl_xor(part, 1);
        part += __shfl_xor(part, 2);
        if (p == 0) s_qb[r][h] = part;
    }

    // ---- phase 0c: u = Wk_h^T Q_h (wave w: head w>>2, cols (w&3)*48) --------
    {
        const int h  = w >> 2;
        const int cb = (w & 3) * 48;
        f32x4 u[3][2];
        #pragma unroll
        for (int ct = 0; ct < 3; ++ct)
            #pragma unroll
            for (int ta = 0; ta < 2; ++ta) u[ct][ta] = (f32x4){0.f,0.f,0.f,0.f};
        #pragma unroll
        for (int kt = 0; kt < 2; ++kt) {
            int ko = kt * 32 + kg * 8;
            bf16x8 bfr[3];
            #pragma unroll
            for (int ct = 0; ct < 3; ++ct)
                bfr[ct] = ldfrag(&WkTb[(size_t)h * 12288 + (size_t)(cb + ct * 16 + rowA) * 64 + ko]);
            #pragma unroll
            for (int ta = 0; ta < 2; ++ta) {
                bf16x8 av = ldfrag(&s_qB[ta * 16 + rowA][h * 64 + ko]);
                #pragma unroll
                for (int ct = 0; ct < 3; ++ct)
                    u[ct][ta] = MFMA(av, bfr[ct], u[ct][ta]);
            }
        }
        #pragma unroll
        for (int ct = 0; ct < 3; ++ct)
            #pragma unroll
            for (int ta = 0; ta < 2; ++ta)
                #pragma unroll
                for (int rgi = 0; rgi < 4; ++rgi) {
                    int rr = ta * 16 + rgrp * 4 + rgi;
                    s_u[rr][h][cb + ct * 16 + col] = u[ct][ta][rgi];
                }
    }
    __syncthreads();

    // ---- phase A: per-wave 4 rows, wave-private, reg-prefetched gather ------
    {
        unsigned short (*kvbuf)[16][200] = (unsigned short (*)[16][200])s_pool64;
        float wt = w_ta[l], bt = b_ta[l];

        for (int rr = 0; rr < 4; ++rr) {
            const int r = w * 4 + rr;
            // write prefetched kv rows to LDS (bf16, packed)
            #pragma unroll
            for (int it = 0; it < 8; ++it)
                *(uint2*)&kvbuf[w][it * 2 + pfn][pfc] = pack4bf(pf[it]);
            // time encoding
            #pragma unroll
            for (int n = 0; n < 16; ++n) {
                float f = s_td[r][n] * wt + bt;
                kvbuf[w][n][128 + l] = f2bf((l & 1) ? __cosf(f) : __sinf(f));
            }
            // issue next row's gather now; latency hides under scores/kvbar
            if (rr < 3) {
                const int rn = r + 1;
                #pragma unroll
                for (int it = 0; it < 8; ++it)
                    pf[it] = *(const float4*)&s_nptr[rn][it * 2 + pfn][pfc];
            }
            __builtin_amdgcn_wave_barrier();

            // scores + masked softmax (wave-internal)
            {
                int h = (l >> 4) & 1, n = l & 15, half = l >> 5;
                float acc = (half == 0) ? s_qb[r][h] : 0.f;
                const unsigned short* kvrow = &kvbuf[w][n][half * 96];
                const float* urow = &s_u[r][h][half * 96];
                #pragma unroll
                for (int k = 0; k < 96; k += 8) {
                    s16x8 kv8 = *(const s16x8*)&kvrow[k];
                    #pragma unroll
                    for (int j = 0; j < 8; ++j)
                        acc += bf2f((unsigned short)kv8[j]) * urow[k + j];
                }
                acc += __shfl_xor(acc, 32);
                int mk = s_mk[r][n];
                float s = mk ? acc * 0.125f : -INFINITY;
                float mx = s;
                #pragma unroll
                for (int m = 1; m < 16; m <<= 1) mx = fmaxf(mx, __shfl_xor(mx, m));
                float p = (mk && mx > -1e37f) ? __expf(s - mx) : 0.f;
                float den = p;
                #pragma unroll
                for (int m = 1; m < 16; m <<= 1) den += __shfl_xor(den, m);
                float a = (den > 0.f) ? (p * rcpf_(den)) : 0.f;
                if (l < 32) s_at[w][h][n] = a;
                if (l == 0 || l == 16) s_satt[r][h] = (den > 0.f) ? 1.f : 0.f;
            }
            __builtin_amdgcn_wave_barrier();

            // kvbar[h][c] via u32-pair LDS reads (2 cols per read)
            #pragma unroll
            for (int ps = 0; ps < 2; ++ps) {
                int cp = (ps == 0) ? l : (64 + l);
                if (!(ps == 1 && l >= 32)) {
                    float ke0 = 0.f, ke1 = 0.f, ko0 = 0.f, ko1 = 0.f;
                    #pragma unroll
                    for (int n = 0; n < 16; ++n) {
                        unsigned pv = *(const unsigned*)&kvbuf[w][n][cp * 2];
                        float ve = bf2f((unsigned short)(pv & 0xFFFFu));
                        float vd = bf2f((unsigned short)(pv >> 16));
                        float a0 = s_at[w][0][n], a1 = s_at[w][1][n];
                        ke0 += a0 * ve; ke1 += a1 * ve;
                        ko0 += a0 * vd; ko1 += a1 * vd;
                    }
                    unsigned o0 = (unsigned)f2bf(ke0) | ((unsigned)f2bf(ko0) << 16);
                    unsigned o1 = (unsigned)f2bf(ke1) | ((unsigned)f2bf(ko1) << 16);
                    *(unsigned*)&s_kvb[r][0][cp * 2] = o0;
                    *(unsigned*)&s_kvb[r][1][cp * 2] = o1;
                }
            }
            __builtin_amdgcn_wave_barrier();
        }
    }
    __syncthreads();

    // ---- phase B: MFMA back-end (pool aliased: kv staging is dead) ----------
    unsigned short (*s_aoB)[136] = (unsigned short (*)[136])s_pool64;
    unsigned short (*s_oB )[136] = (unsigned short (*)[136])((char*)s_pool64 + 8704);
    unsigned short (*s_h1B)[136] = (unsigned short (*)[136])((char*)s_pool64 + 17408);
    float          (*s_h2 )[128] = (float          (*)[128])((char*)s_pool64 + 26112);

    // out = Wv_h @ kvbar_h + satt_h*bv : wave w -> head w>>2, cols (w&3)*16
    {
        const int h  = w >> 2;
        const int c0 = (w & 3) * 16;
        f32x4 o0 = {0.f,0.f,0.f,0.f}, o1 = {0.f,0.f,0.f,0.f};
        #pragma unroll
        for (int kt = 0; kt < 6; ++kt) {
            int ko = kt * 32 + kg * 8;
            bf16x8 bfr = ldfrag(&Wvb[(size_t)(h * 64 + c0 + rowA) * 192 + ko]);
            o0 = MFMA(ldfrag(&s_kvb[     rowA][h][ko]), bfr, o0);
            o1 = MFMA(ldfrag(&s_kvb[16 + rowA][h][ko]), bfr, o1);
        }
        int d0 = h * 64 + c0 + col;
        float bv0 = bv[d0];
        #pragma unroll
        for (int rgi = 0; rgi < 4; ++rgi) {
            int rb = rgrp * 4 + rgi;
            s_oB[rb     ][d0] = f2bf(o0[rgi] + s_satt[rb     ][h] * bv0);
            s_oB[rb + 16][d0] = f2bf(o1[rgi] + s_satt[rb + 16][h] * bv0);
        }
    }
    __syncthreads();

    // ao = Wo @ out + bo
    {
        const int n0 = w * 16;
        f32x4 a0 = {0.f,0.f,0.f,0.f}, a1 = {0.f,0.f,0.f,0.f};
        #pragma unroll
        for (int kt = 0; kt < 4; ++kt) {
            int ko = kt * 32 + kg * 8;
            bf16x8 bfr = ldfrag(&Wob[(size_t)(n0 + rowA) * 128 + ko]);
            a0 = MFMA(ldfrag(&s_oB[     rowA][ko]), bfr, a0);
            a1 = MFMA(ldfrag(&s_oB[16 + rowA][ko]), bfr, a1);
        }
        float bb = bo[n0 + col];
        #pragma unroll
        for (int rgi = 0; rgi < 4; ++rgi) {
            int rb = rgrp * 4 + rgi;
            s_aoB[rb     ][n0 + col] = f2bf(a0[rgi] + bb);
            s_aoB[rb + 16][n0 + col] = f2bf(a1[rgi] + bb);
        }
    }
    __syncthreads();

    // h1 = relu(Wm1 @ [ao|nf] + bm1), K=256 (kt 0..3: ao, kt 4..7: nf)
    {
        const int n0 = w * 16;
        f32x4 a0 = {0.f,0.f,0.f,0.f}, a1 = {0.f,0.f,0.f,0.f};
        #pragma unroll
        for (int kt = 0; kt < 8; ++kt) {
            int ko = kt * 32 + kg * 8;
            bf16x8 av0 = (kt < 4) ? ldfrag(&s_aoB[     rowA][ko])
                                  : ldfrag(&s_nfB[     rowA][ko - 128]);
            bf16x8 av1 = (kt < 4) ? ldfrag(&s_aoB[16 + rowA][ko])
                                  : ldfrag(&s_nfB[16 + rowA][ko - 128]);
            bf16x8 bfr = ldfrag(&Wm1b[(size_t)(n0 + rowA) * 256 + ko]);
            a0 = MFMA(av0, bfr, a0);
            a1 = MFMA(av1, bfr, a1);
        }
        float bb = bm1[n0 + col];
        #pragma unroll
        for (int rgi = 0; rgi < 4; ++rgi) {
            int rb = rgrp * 4 + rgi;
            s_h1B[rb     ][n0 + col] = f2bf(fmaxf(a0[rgi] + bb, 0.f));
            s_h1B[rb + 16][n0 + col] = f2bf(fmaxf(a1[rgi] + bb, 0.f));
        }
    }
    __syncthreads();

    // h2 = Wm2 @ h1 + bm2 -> f32
    {
        const int n0 = w * 16;
        f32x4 a0 = {0.f,0.f,0.f,0.f}, a1 = {0.f,0.f,0.f,0.f};
        #pragma unroll
        for (int kt = 0; kt < 4; ++kt) {
            int ko = kt * 32 + kg * 8;
            bf16x8 bfr = ldfrag(&Wm2b[(size_t)(n0 + rowA) * 128 + ko]);
            a0 = MFMA(ldfrag(&s_h1B[     rowA][ko]), bfr, a0);
            a1 = MFMA(ldfrag(&s_h1B[16 + rowA][ko]), bfr, a1);
        }
        float bb = bm2[n0 + col];
        #pragma unroll
        for (int rgi = 0; rgi < 4; ++rgi) {
            int rb = rgrp * 4 + rgi;
            s_h2[rb     ][n0 + col] = a0[rgi] + bb;
            s_h2[rb + 16][n0 + col] = a1[rgi] + bb;
        }
    }
    __syncthreads();

    // LayerNorm: wave w -> rows w*4 .. w*4+3
    {
        float lg0 = ln_g[l], lg1 = ln_g[64 + l];
        float lb0 = ln_b[l], lb1 = ln_b[64 + l];
        #pragma unroll
        for (int i = 0; i < 4; ++i) {
            int r = w * 4 + i;
            float v0 = s_h2[r][l], v1 = s_h2[r][64 + l];
            float sum = v0 + v1;
            #pragma unroll
            for (int m = 1; m < 64; m <<= 1) sum += __shfl_xor(sum, m);
            float mean = sum * (1.f / 128.f);
            float e0 = v0 - mean, e1 = v1 - mean;
            float sq = e0 * e0 + e1 * e1;
            #pragma unroll
            for (int m = 1; m < 64; m <<= 1) sq += __shfl_xor(sq, m);
            float inv = rsqrtf(sq * (1.f / 128.f) + 1e-5f);
            out[(size_t)(base + r) * DIM + l]      = e0 * inv * lg0 + lb0;
            out[(size_t)(base + r) * DIM + 64 + l] = e1 * inv * lg1 + lb1;
        }
    }
}

// ---------------------------------------------------------------------------
extern "C" void kernel_launch(void* const* d_in, const int* in_sizes, int n_in,
                              void* d_out, int out_size, void* d_ws, size_t ws_size,
                              hipStream_t stream) {
    const int*   src         = (const int*)  d_in[0];
    const int*   dst         = (const int*)  d_in[1];
    const float* ts          = (const float*)d_in[2];
    const int*   nbr_ids     = (const int*)  d_in[3];
    const float* nbr_ts      = (const float*)d_in[4];
    const float* memory      = (const float*)d_in[5];
    const float* last_update = (const float*)d_in[6];
    const float* w_t_msg     = (const float*)d_in[7];
    const float* b_t_msg     = (const float*)d_in[8];
    const float* W_msg1      = (const float*)d_in[9];
    const float* b_msg1      = (const float*)d_in[10];
    const float* W_msg2      = (const float*)d_in[11];
    const float* b_msg2      = (const float*)d_in[12];
    const float* W_ih        = (const float*)d_in[13];
    const float* b_ih        = (const float*)d_in[14];
    const float* W_hh        = (const float*)d_in[15];
    const float* b_hh        = (const float*)d_in[16];
    const float* w_t_att     = (const float*)d_in[17];
    const float* b_t_att     = (const float*)d_in[18];
    const float* Wq          = (const float*)d_in[19];
    const float* bq          = (const float*)d_in[20];
    const float* Wk          = (const float*)d_in[21];
    const float* bk          = (const float*)d_in[22];
    const float* Wv          = (const float*)d_in[23];
    const float* bv          = (const float*)d_in[24];
    const float* Wo          = (const float*)d_in[25];
    const float* bo          = (const float*)d_in[26];
    const float* Wm1         = (const float*)d_in[27];
    const float* bm1         = (const float*)d_in[28];
    const float* Wm2         = (const float*)d_in[29];
    const float* bm2         = (const float*)d_in[30];
    const float* ln_g        = (const float*)d_in[31];
    const float* ln_b        = (const float*)d_in[32];
    float* out = (float*)d_out;

    char* ws = (char*)d_ws;
    size_t off = 0;
    float* new_mem = (float*)(ws + off); off += (size_t)2 * BATCH * DIM * 4;   // 8 MiB
    int*   winner  = (int*)  (ws + off); off += 2097152;                       // 2 MiB
    int*   sel_id  = (int*)  (ws + off); off += (size_t)BATCH * KSEL * 4;
    float* sel_td  = (float*)(ws + off); off += (size_t)BATCH * KSEL * 4;
    int*   sel_mk  = (int*)  (ws + off); off += (size_t)BATCH * KSEL * 4;
    unsigned short* Wpool = (unsigned short*)(ws + off); off += (size_t)CVT_TOT * 2;

    k_prep<<<NB_CVT, 256, 0, stream>>>(
        W_msg1, W_msg2, W_ih, W_hh, Wq, Wv, Wo, Wm1, Wm2, Wk, Wpool, winner);
    k1_mfma<<<(2 * BATCH) / 64, 512, 0, stream>>>(
        src, dst, ts, memory, last_update,
        w_t_msg, b_t_msg, Wpool, b_msg1, b_msg2, b_ih, b_hh, new_mem,
        winner, nbr_ids, nbr_ts, sel_id, sel_td, sel_mk);
    k3_fused<<<BATCH / 32, 512, 0, stream>>>(
        src, memory, new_mem, winner, sel_id, sel_td, sel_mk,
        w_t_att, b_t_att, Wpool, bq, bk, bv, bo, bm1, bm2, ln_g, ln_b, out);
}